// Round 1
// baseline (600.982 us; speedup 1.0000x reference)
//
#include <hip/hip_runtime.h>
#include <cstddef>

#define B_  2
#define T_  2048
#define C_  1024
#define H_  16
#define D_  64
#define M_  64
#define NC_ 32   // number of chunks = T/64
#define CH_ 64   // chunk length

// ---------------- K0a: combined projection weights ----------------
// Wbig[c][j], j in [0,1024): q'-col (h=j/64, m=j%64)  = sum_d Wqkv[h*64+d][c]*proj[h][d][m]
//             j in [1024,2048): k'-col                 = sum_d Wqkv[1024+h*64+d][c]*proj[h][d][m]
//             j in [2048,3072): v-col                  = Wqkv[j][c]
__global__ void build_wbig(const float* __restrict__ Wqkv,
                           const float* __restrict__ proj,
                           float* __restrict__ Wbig) {
    const int total = C_ * 3072;
    for (int idx = blockIdx.x * blockDim.x + threadIdx.x; idx < total;
         idx += gridDim.x * blockDim.x) {
        int c = idx / 3072;
        int j = idx - c * 3072;
        float val;
        if (j < 2048) {
            int sel = j >> 10;          // 0 = q, 1 = k
            int hm  = j & 1023;
            int h = hm >> 6, m = hm & 63;
            const float* wcol = Wqkv + (size_t)(sel * C_ + h * D_) * C_ + c; // + d*C_
            const float* p    = proj + (size_t)h * D_ * M_ + m;              // + d*M_
            float acc = 0.f;
#pragma unroll 8
            for (int d = 0; d < D_; ++d)
                acc += wcol[(size_t)d * C_] * p[(size_t)d * M_];
            val = acc;
        } else {
            val = Wqkv[(size_t)j * C_ + c];
        }
        Wbig[(size_t)c * 3072 + j] = val;
    }
}

__global__ void build_bbig(const float* __restrict__ bqkv,
                           const float* __restrict__ proj,
                           float* __restrict__ bbig) {
    int j = blockIdx.x * blockDim.x + threadIdx.x;
    if (j >= 3072) return;
    if (j < 2048) {
        int sel = j >> 10;
        int hm  = j & 1023;
        int h = hm >> 6, m = hm & 63;
        const float* b = bqkv + sel * C_ + h * D_;
        const float* p = proj + (size_t)h * D_ * M_ + m;
        float acc = 0.f;
#pragma unroll 8
        for (int d = 0; d < D_; ++d) acc += b[d] * p[(size_t)d * M_];
        bbig[j] = acc;
    } else {
        bbig[j] = bqkv[j];
    }
}

// ---------------- K0c: transpose Wout (1024x1024) so GEMM2's B is [K][N] ----------------
__global__ void transpose1024(const float* __restrict__ in, float* __restrict__ outT) {
    __shared__ float tile[32][33];
    int bx = blockIdx.x & 31, by = blockIdx.x >> 5;
    int tx = threadIdx.x & 31, ty = threadIdx.x >> 5;   // ty 0..7
#pragma unroll
    for (int r = 0; r < 32; r += 8)
        tile[ty + r][tx] = in[(size_t)(by * 32 + ty + r) * 1024 + bx * 32 + tx];
    __syncthreads();
#pragma unroll
    for (int r = 0; r < 32; r += 8)
        outT[(size_t)(bx * 32 + ty + r) * 1024 + by * 32 + tx] = tile[tx][ty + r];
}

// ---------------- GEMM: C[M][N] = act(A[M][K] @ B[K][N] + bias[N]) ----------------
// act = relu for columns < reluLimit. M,N multiples of 64, K multiple of 16.
__global__ __launch_bounds__(256) void gemm_bias_act(
    const float* __restrict__ A, const float* __restrict__ B,
    const float* __restrict__ bias, float* __restrict__ C,
    int M, int N, int K, int reluLimit) {
    __shared__ float As[16][68];   // As[k][m] (transposed A tile)
    __shared__ float Bs[16][68];   // Bs[k][n]
    const int tid = threadIdx.x;
    const int m0 = blockIdx.y * 64;
    const int n0 = blockIdx.x * 64;
    const int arow  = tid >> 2;          // 0..63
    const int akq   = (tid & 3) * 4;     // 0,4,8,12
    const int bkrow = tid >> 4;          // 0..15
    const int bncol = (tid & 15) * 4;
    const int mB = (tid >> 4) * 4;
    const int nB = (tid & 15) * 4;
    float acc[4][4] = {{0.f}};
    const float* Aptr = A + (size_t)(m0 + arow) * K + akq;
    const float* Bptr = B + (size_t)bkrow * N + n0 + bncol;
    for (int k0 = 0; k0 < K; k0 += 16) {
        float4 av = *(const float4*)(Aptr + k0);
        float4 bv = *(const float4*)(Bptr + (size_t)k0 * N);
        __syncthreads();
        As[akq + 0][arow] = av.x;
        As[akq + 1][arow] = av.y;
        As[akq + 2][arow] = av.z;
        As[akq + 3][arow] = av.w;
        *(float4*)&Bs[bkrow][bncol] = bv;
        __syncthreads();
#pragma unroll
        for (int kk = 0; kk < 16; ++kk) {
            float4 a = *(const float4*)&As[kk][mB];
            float4 b = *(const float4*)&Bs[kk][nB];
            acc[0][0] += a.x * b.x; acc[0][1] += a.x * b.y; acc[0][2] += a.x * b.z; acc[0][3] += a.x * b.w;
            acc[1][0] += a.y * b.x; acc[1][1] += a.y * b.y; acc[1][2] += a.y * b.z; acc[1][3] += a.y * b.w;
            acc[2][0] += a.z * b.x; acc[2][1] += a.z * b.y; acc[2][2] += a.z * b.z; acc[2][3] += a.z * b.w;
            acc[3][0] += a.w * b.x; acc[3][1] += a.w * b.y; acc[3][2] += a.w * b.z; acc[3][3] += a.w * b.w;
        }
    }
#pragma unroll
    for (int i = 0; i < 4; ++i) {
        int row = m0 + mB + i;
#pragma unroll
        for (int j = 0; j < 4; ++j) {
            int col = n0 + nB + j;
            float v = acc[i][j] + bias[col];
            if (col < reluLimit) v = fmaxf(v, 0.f);
            C[(size_t)row * N + col] = v;
        }
    }
}

// ---------------- K2: per-chunk local sums: Ksum[m], KV[m][d] = sum_t k'[t][m]*v[t][d] ----------------
__global__ __launch_bounds__(256) void chunk_kv_sums(
    const float* __restrict__ out1, float* __restrict__ chunkKV,
    float* __restrict__ chunkKs) {
    __shared__ float Kl[64][68];
    __shared__ float Vl[64][68];
    const int blk = blockIdx.x;             // bh*NC + c
    const int c  = blk & (NC_ - 1);
    const int bh = blk >> 5;
    const int b = bh >> 4, h = bh & 15;
    const int t0 = c * CH_;
    const float* kbase = out1 + (size_t)(b * T_ + t0) * 3072 + C_ + h * D_;
    const float* vbase = kbase + C_;
    const int tid = threadIdx.x;
    for (int i = tid; i < 64 * 16; i += 256) {
        int t = i >> 4, q = (i & 15) * 4;
        *(float4*)&Kl[t][q] = *(const float4*)(kbase + (size_t)t * 3072 + q);
        *(float4*)&Vl[t][q] = *(const float4*)(vbase + (size_t)t * 3072 + q);
    }
    __syncthreads();
    const int mB = (tid >> 4) * 4, dB = (tid & 15) * 4;
    float acc[4][4] = {{0.f}};
#pragma unroll 4
    for (int t = 0; t < 64; ++t) {
        float4 k4 = *(const float4*)&Kl[t][mB];
        float4 v4 = *(const float4*)&Vl[t][dB];
        acc[0][0] += k4.x * v4.x; acc[0][1] += k4.x * v4.y; acc[0][2] += k4.x * v4.z; acc[0][3] += k4.x * v4.w;
        acc[1][0] += k4.y * v4.x; acc[1][1] += k4.y * v4.y; acc[1][2] += k4.y * v4.z; acc[1][3] += k4.y * v4.w;
        acc[2][0] += k4.z * v4.x; acc[2][1] += k4.z * v4.y; acc[2][2] += k4.z * v4.z; acc[2][3] += k4.z * v4.w;
        acc[3][0] += k4.w * v4.x; acc[3][1] += k4.w * v4.y; acc[3][2] += k4.w * v4.z; acc[3][3] += k4.w * v4.w;
    }
    float* kvout = chunkKV + (size_t)blk * (M_ * D_);
#pragma unroll
    for (int i = 0; i < 4; ++i)
#pragma unroll
        for (int j = 0; j < 4; ++j)
            kvout[(mB + i) * 64 + dB + j] = acc[i][j];
    if (tid < 64) {
        float s = 0.f;
#pragma unroll 8
        for (int t = 0; t < 64; ++t) s += Kl[t][tid];
        chunkKs[(size_t)blk * 64 + tid] = s;
    }
}

// ---------------- K3: exclusive prefix over chunks (per b,h) ----------------
__global__ __launch_bounds__(256) void chunk_scan(float* chunkKV, float* chunkKs) {
    const int bh = blockIdx.x;   // 0..31
    const int tid = threadIdx.x;
    for (int i = tid; i < M_ * D_; i += 256) {
        float run = 0.f;
        float* p = chunkKV + (size_t)bh * NC_ * (M_ * D_) + i;
        for (int c = 0; c < NC_; ++c) {
            float v = p[(size_t)c * (M_ * D_)];
            p[(size_t)c * (M_ * D_)] = run;
            run += v;
        }
    }
    if (tid < 64) {
        float run = 0.f;
        float* p = chunkKs + (size_t)bh * NC_ * 64 + tid;
        for (int c = 0; c < NC_; ++c) {
            float v = p[c * 64];
            p[c * 64] = run;
            run += v;
        }
    }
}

// ---------------- K4: per-chunk attention ----------------
// ctx[t][d] = sum_m Q[t][m]*S[m][d] + sum_{s<=t} A[t][s]*V[s][d],  A[t][s] = sum_m Q[t][m]*K[s][m]
// norm[t]   = sum_m Q[t][m]*sK[m]   + sum_{s<=t} A[t][s]
__global__ __launch_bounds__(256) void chunk_attn(
    const float* __restrict__ out1, const float* __restrict__ chunkKV,
    const float* __restrict__ chunkKs, float* __restrict__ attnOut) {
    __shared__ float Ql[64][68];
    __shared__ float KVl[64][68];    // first K, then reused for V
    __shared__ float Sl[64][68];     // S[m][d] exclusive prefix
    __shared__ float Al[64][68];     // masked A[t][s]
    __shared__ float sK[64];
    __shared__ float nrm[64];
    const int blk = blockIdx.x;
    const int c = blk & 31, bh = blk >> 5;
    const int b = bh >> 4, h = bh & 15;
    const int t0 = c * CH_;
    const float* qbase = out1 + (size_t)(b * T_ + t0) * 3072 + h * D_;
    const float* kbase = qbase + C_;
    const float* vbase = qbase + 2 * C_;
    const float* Sbase = chunkKV + (size_t)blk * (M_ * D_);
    const int tid = threadIdx.x;
    for (int i = tid; i < 64 * 16; i += 256) {
        int t = i >> 4, q = (i & 15) * 4;
        *(float4*)&Ql[t][q]  = *(const float4*)(qbase + (size_t)t * 3072 + q);
        *(float4*)&KVl[t][q] = *(const float4*)(kbase + (size_t)t * 3072 + q);
        *(float4*)&Sl[t][q]  = *(const float4*)(Sbase + t * 64 + q);
    }
    if (tid < 64) sK[tid] = chunkKs[(size_t)blk * 64 + tid];
    __syncthreads();
    const int tB = (tid >> 4) * 4, sB = (tid & 15) * 4;
    {
        float a[4][4] = {{0.f}};
#pragma unroll 4
        for (int m = 0; m < 64; ++m) {
            float q0 = Ql[tB + 0][m], q1 = Ql[tB + 1][m], q2 = Ql[tB + 2][m], q3 = Ql[tB + 3][m];
            float k0 = KVl[sB + 0][m], k1 = KVl[sB + 1][m], k2 = KVl[sB + 2][m], k3 = KVl[sB + 3][m];
            a[0][0] += q0 * k0; a[0][1] += q0 * k1; a[0][2] += q0 * k2; a[0][3] += q0 * k3;
            a[1][0] += q1 * k0; a[1][1] += q1 * k1; a[1][2] += q1 * k2; a[1][3] += q1 * k3;
            a[2][0] += q2 * k0; a[2][1] += q2 * k1; a[2][2] += q2 * k2; a[2][3] += q2 * k3;
            a[3][0] += q3 * k0; a[3][1] += q3 * k1; a[3][2] += q3 * k2; a[3][3] += q3 * k3;
        }
#pragma unroll
        for (int i = 0; i < 4; ++i)
#pragma unroll
            for (int j = 0; j < 4; ++j)
                Al[tB + i][sB + j] = (sB + j <= tB + i) ? a[i][j] : 0.f;
    }
    __syncthreads();
    // reuse KVl for V
    for (int i = tid; i < 64 * 16; i += 256) {
        int t = i >> 4, q = (i & 15) * 4;
        *(float4*)&KVl[t][q] = *(const float4*)(vbase + (size_t)t * 3072 + q);
    }
    if (tid < 64) {
        float s = 0.f;
#pragma unroll 8
        for (int m = 0; m < 64; ++m) s += Ql[tid][m] * sK[m];
        for (int s2 = 0; s2 <= tid; ++s2) s += Al[tid][s2];
        nrm[tid] = s + 1e-6f;
    }
    __syncthreads();
    const int dB = sB;
    float acc[4][4] = {{0.f}};
#pragma unroll 4
    for (int m = 0; m < 64; ++m) {
        float q0 = Ql[tB + 0][m], q1 = Ql[tB + 1][m], q2 = Ql[tB + 2][m], q3 = Ql[tB + 3][m];
        float4 sv = *(const float4*)&Sl[m][dB];
        acc[0][0] += q0 * sv.x; acc[0][1] += q0 * sv.y; acc[0][2] += q0 * sv.z; acc[0][3] += q0 * sv.w;
        acc[1][0] += q1 * sv.x; acc[1][1] += q1 * sv.y; acc[1][2] += q1 * sv.z; acc[1][3] += q1 * sv.w;
        acc[2][0] += q2 * sv.x; acc[2][1] += q2 * sv.y; acc[2][2] += q2 * sv.z; acc[2][3] += q2 * sv.w;
        acc[3][0] += q3 * sv.x; acc[3][1] += q3 * sv.y; acc[3][2] += q3 * sv.z; acc[3][3] += q3 * sv.w;
    }
#pragma unroll 4
    for (int s2 = 0; s2 < 64; ++s2) {
        float a0 = Al[tB + 0][s2], a1 = Al[tB + 1][s2], a2 = Al[tB + 2][s2], a3 = Al[tB + 3][s2];
        float4 vv = *(const float4*)&KVl[s2][dB];
        acc[0][0] += a0 * vv.x; acc[0][1] += a0 * vv.y; acc[0][2] += a0 * vv.z; acc[0][3] += a0 * vv.w;
        acc[1][0] += a1 * vv.x; acc[1][1] += a1 * vv.y; acc[1][2] += a1 * vv.z; acc[1][3] += a1 * vv.w;
        acc[2][0] += a2 * vv.x; acc[2][1] += a2 * vv.y; acc[2][2] += a2 * vv.z; acc[2][3] += a2 * vv.w;
        acc[3][0] += a3 * vv.x; acc[3][1] += a3 * vv.y; acc[3][2] += a3 * vv.z; acc[3][3] += a3 * vv.w;
    }
#pragma unroll
    for (int i = 0; i < 4; ++i) {
        float inv = 1.f / nrm[tB + i];
#pragma unroll
        for (int j = 0; j < 4; ++j)
            attnOut[(size_t)(b * T_ + t0 + tB + i) * C_ + h * D_ + dB + j] = acc[i][j] * inv;
    }
}

extern "C" void kernel_launch(void* const* d_in, const int* in_sizes, int n_in,
                              void* d_out, int out_size, void* d_ws, size_t ws_size,
                              hipStream_t stream) {
    (void)in_sizes; (void)n_in; (void)out_size; (void)ws_size;
    const float* x    = (const float*)d_in[0];
    const float* Wqkv = (const float*)d_in[1];
    const float* bqkv = (const float*)d_in[2];
    const float* Wout = (const float*)d_in[3];
    const float* bout = (const float*)d_in[4];
    const float* proj = (const float*)d_in[5];
    float* out = (float*)d_out;
    float* ws  = (float*)d_ws;

    float* Wbig  = ws;                          // 1024*3072
    float* bbig  = Wbig + 1024 * 3072;          // 3072
    float* out1  = bbig + 3072;                 // 4096*3072  (q'|k'|v)
    float* ckv   = out1 + 4096 * 3072;          // 32*32*4096
    float* cks   = ckv + 32 * 32 * 4096;        // 32*32*64
    float* attn  = cks + 32 * 32 * 64;          // 4096*1024
    float* WoutT = attn + 4096 * 1024;          // 1024*1024

    build_wbig<<<2048, 256, 0, stream>>>(Wqkv, proj, Wbig);
    build_bbig<<<12, 256, 0, stream>>>(bqkv, proj, bbig);
    transpose1024<<<1024, 256, 0, stream>>>(Wout, WoutT);
    gemm_bias_act<<<dim3(48, 64), 256, 0, stream>>>(x, Wbig, bbig, out1,
                                                    4096, 3072, 1024, 2048);
    chunk_kv_sums<<<1024, 256, 0, stream>>>(out1, ckv, cks);
    chunk_scan<<<32, 256, 0, stream>>>(ckv, cks);
    chunk_attn<<<1024, 256, 0, stream>>>(out1, ckv, cks, attn);
    gemm_bias_act<<<dim3(16, 64), 256, 0, stream>>>(attn, WoutT, bout, out,
                                                    4096, 1024, 1024, 0);
}

// Round 2
// 192.263 us; speedup vs baseline: 3.1258x; 3.1258x over previous
//
#include <hip/hip_runtime.h>
#include <cstddef>

#define B_  2
#define T_  2048
#define C_  1024
#define H_  16
#define D_  64
#define M_  64
#define NC_ 32   // number of chunks = T/64
#define CH_ 64   // chunk length

typedef __attribute__((ext_vector_type(8))) short bf16x8;
typedef __attribute__((ext_vector_type(4))) float f32x4;

__device__ __forceinline__ ushort f2bf(float f) {
    union { float f; unsigned u; } v; v.f = f;
    unsigned r = v.u + 0x7FFF + ((v.u >> 16) & 1);   // RNE
    return (ushort)(r >> 16);
}

__device__ __forceinline__ void gld_lds16(const ushort* g, ushort* lds) {
    __builtin_amdgcn_global_load_lds(
        (const __attribute__((address_space(1))) unsigned int*)g,
        (__attribute__((address_space(3))) unsigned int*)lds,
        16, 0, 0);
}

// ---------------- build combined projection weights, bf16, [N=3072][K=1024] ----------------
// Wbt[j][c]: j<1024  : sum_d Wqkv[h*64+d][c]*proj[h][d][m]      (h=j/64, m=j%64)
//            j<2048  : sum_d Wqkv[1024+h*64+d][c]*proj[h][d][m]
//            j>=2048 : Wqkv[j][c]
__global__ __launch_bounds__(256) void build_wbigT(const float* __restrict__ Wqkv,
                                                   const float* __restrict__ proj,
                                                   ushort* __restrict__ Wbt) {
    const int j = blockIdx.x;            // 0..3071
    const int c0 = threadIdx.x * 4;      // 4 consecutive c per thread
    float4 acc = {0.f, 0.f, 0.f, 0.f};
    if (j < 2048) {
        const int sel = j >> 10, hm = j & 1023, h = hm >> 6, m = hm & 63;
        const float* wrow = Wqkv + (size_t)(sel * C_ + h * D_) * C_ + c0;  // + d*C_
        const float* p    = proj + (size_t)h * D_ * M_ + m;                // + d*M_
#pragma unroll 4
        for (int d = 0; d < D_; ++d) {
            float pv = p[(size_t)d * M_];
            float4 wv = *(const float4*)(wrow + (size_t)d * C_);
            acc.x += wv.x * pv; acc.y += wv.y * pv;
            acc.z += wv.z * pv; acc.w += wv.w * pv;
        }
    } else {
        acc = *(const float4*)(Wqkv + (size_t)j * C_ + c0);
    }
    ushort4 o = { f2bf(acc.x), f2bf(acc.y), f2bf(acc.z), f2bf(acc.w) };
    *(ushort4*)&Wbt[(size_t)j * C_ + c0] = o;
}

__global__ void build_bbig(const float* __restrict__ bqkv,
                           const float* __restrict__ proj,
                           float* __restrict__ bbig) {
    int j = blockIdx.x * blockDim.x + threadIdx.x;
    if (j >= 3072) return;
    if (j < 2048) {
        int sel = j >> 10, hm = j & 1023, h = hm >> 6, m = hm & 63;
        const float* b = bqkv + sel * C_ + h * D_;
        const float* p = proj + (size_t)h * D_ * M_ + m;
        float acc = 0.f;
#pragma unroll 8
        for (int d = 0; d < D_; ++d) acc += b[d] * p[(size_t)d * M_];
        bbig[j] = acc;
    } else {
        bbig[j] = bqkv[j];
    }
}

// ---------------- fp32 -> bf16 cast (packed x4) ----------------
__global__ void cast_f32_bf16(const float* __restrict__ in, ushort* __restrict__ out, int n4) {
    int i = blockIdx.x * blockDim.x + threadIdx.x;
    if (i >= n4) return;
    float4 v = ((const float4*)in)[i];
    ushort4 o = { f2bf(v.x), f2bf(v.y), f2bf(v.z), f2bf(v.w) };
    ((ushort4*)out)[i] = o;
}

// ---------------- MFMA GEMM: C[M][N] = act(A[M][K] @ Bt[N][K]^T + bias) ----------------
// m97 structure: 128x128 tile, 4 waves (2x2), BK=32, global_load_lds w=16, 2-barrier loop.
__global__ __launch_bounds__(256, 2) void gemm_mfma_bt(
    const ushort* __restrict__ A,    // [M][K] bf16
    const ushort* __restrict__ Bt,   // [N][K] bf16
    const float* __restrict__ bias,  // [N]
    float* __restrict__ Cmat,        // [M][N] fp32
    int M, int N, int K, int reluLimit)
{
    __shared__ __align__(16) ushort As[128 * 32];
    __shared__ __align__(16) ushort Bs[128 * 32];
    const int tid  = threadIdx.x;
    const int wave = tid >> 6, lane = tid & 63;
    const int m0 = blockIdx.y * 128, n0 = blockIdx.x * 128;
    const int wr = (wave >> 1) * 64, wc = (wave & 1) * 64;
    f32x4 acc[4][4] = {};

    // staging: each wave fills two 1024B chunks (16 rows each) of As and Bs
    const int lrow = lane >> 2;          // row within 16-row chunk
    const int lcol = (lane & 3) * 8;     // ushort offset of 16B slice in 64B row
    ushort* AsB0 = &As[(wave * 2 + 0) * 512];
    ushort* AsB1 = &As[(wave * 2 + 1) * 512];
    ushort* BsB0 = &Bs[(wave * 2 + 0) * 512];
    ushort* BsB1 = &Bs[(wave * 2 + 1) * 512];
    const ushort* Ag0 = A  + (size_t)(m0 + wave * 32 + lrow) * K + lcol;
    const ushort* Ag1 = Ag0 + (size_t)16 * K;
    const ushort* Bg0 = Bt + (size_t)(n0 + wave * 32 + lrow) * K + lcol;
    const ushort* Bg1 = Bg0 + (size_t)16 * K;

    const int frow = lane & 15, fk = (lane >> 4) * 8;   // fragment read coords

    for (int k0 = 0; k0 < K; k0 += 32) {
        __syncthreads();
        gld_lds16(Ag0 + k0, AsB0);
        gld_lds16(Ag1 + k0, AsB1);
        gld_lds16(Bg0 + k0, BsB0);
        gld_lds16(Bg1 + k0, BsB1);
        __syncthreads();
        bf16x8 af[4], bfr[4];
#pragma unroll
        for (int i = 0; i < 4; ++i)
            af[i] = *(const bf16x8*)&As[(wr + i * 16 + frow) * 32 + fk];
#pragma unroll
        for (int j = 0; j < 4; ++j)
            bfr[j] = *(const bf16x8*)&Bs[(wc + j * 16 + frow) * 32 + fk];
#pragma unroll
        for (int i = 0; i < 4; ++i)
#pragma unroll
            for (int j = 0; j < 4; ++j)
                acc[i][j] = __builtin_amdgcn_mfma_f32_16x16x32_bf16(af[i], bfr[j], acc[i][j], 0, 0, 0);
    }

    // epilogue: D col=lane&15, row=(lane>>4)*4+r  [verified m89/m91]
    const int crow = (lane >> 4) * 4, ccol = lane & 15;
#pragma unroll
    for (int j = 0; j < 4; ++j) {
        int col = n0 + wc + j * 16 + ccol;
        float bv = bias[col];
        bool rl = col < reluLimit;
#pragma unroll
        for (int i = 0; i < 4; ++i) {
#pragma unroll
            for (int r = 0; r < 4; ++r) {
                int row = m0 + wr + i * 16 + crow + r;
                float v = acc[i][j][r] + bv;
                if (rl) v = fmaxf(v, 0.f);
                Cmat[(size_t)row * N + col] = v;
            }
        }
    }
}

// ---------------- K2: per-chunk local sums ----------------
__global__ __launch_bounds__(256) void chunk_kv_sums(
    const float* __restrict__ out1, float* __restrict__ chunkKV,
    float* __restrict__ chunkKs) {
    __shared__ float Kl[64][68];
    __shared__ float Vl[64][68];
    const int blk = blockIdx.x;
    const int bh = blk >> 5;
    const int b = bh >> 4, h = bh & 15;
    const int t0 = (blk & (NC_ - 1)) * CH_;
    const float* kbase = out1 + (size_t)(b * T_ + t0) * 3072 + C_ + h * D_;
    const float* vbase = kbase + C_;
    const int tid = threadIdx.x;
    for (int i = tid; i < 64 * 16; i += 256) {
        int t = i >> 4, q = (i & 15) * 4;
        *(float4*)&Kl[t][q] = *(const float4*)(kbase + (size_t)t * 3072 + q);
        *(float4*)&Vl[t][q] = *(const float4*)(vbase + (size_t)t * 3072 + q);
    }
    __syncthreads();
    const int mB = (tid >> 4) * 4, dB = (tid & 15) * 4;
    float acc[4][4] = {{0.f}};
#pragma unroll 4
    for (int t = 0; t < 64; ++t) {
        float4 k4 = *(const float4*)&Kl[t][mB];
        float4 v4 = *(const float4*)&Vl[t][dB];
        acc[0][0] += k4.x * v4.x; acc[0][1] += k4.x * v4.y; acc[0][2] += k4.x * v4.z; acc[0][3] += k4.x * v4.w;
        acc[1][0] += k4.y * v4.x; acc[1][1] += k4.y * v4.y; acc[1][2] += k4.y * v4.z; acc[1][3] += k4.y * v4.w;
        acc[2][0] += k4.z * v4.x; acc[2][1] += k4.z * v4.y; acc[2][2] += k4.z * v4.z; acc[2][3] += k4.z * v4.w;
        acc[3][0] += k4.w * v4.x; acc[3][1] += k4.w * v4.y; acc[3][2] += k4.w * v4.z; acc[3][3] += k4.w * v4.w;
    }
    float* kvout = chunkKV + (size_t)blk * (M_ * D_);
#pragma unroll
    for (int i = 0; i < 4; ++i)
#pragma unroll
        for (int j = 0; j < 4; ++j)
            kvout[(mB + i) * 64 + dB + j] = acc[i][j];
    if (tid < 64) {
        float s = 0.f;
#pragma unroll 8
        for (int t = 0; t < 64; ++t) s += Kl[t][tid];
        chunkKs[(size_t)blk * 64 + tid] = s;
    }
}

// ---------------- K3: exclusive prefix over chunks (per b,h) ----------------
__global__ __launch_bounds__(256) void chunk_scan(float* chunkKV, float* chunkKs) {
    const int bh = blockIdx.x;
    const int tid = threadIdx.x;
    for (int i = tid; i < M_ * D_; i += 256) {
        float run = 0.f;
        float* p = chunkKV + (size_t)bh * NC_ * (M_ * D_) + i;
        for (int c = 0; c < NC_; ++c) {
            float v = p[(size_t)c * (M_ * D_)];
            p[(size_t)c * (M_ * D_)] = run;
            run += v;
        }
    }
    if (tid < 64) {
        float run = 0.f;
        float* p = chunkKs + (size_t)bh * NC_ * 64 + tid;
        for (int c = 0; c < NC_; ++c) {
            float v = p[c * 64];
            p[c * 64] = run;
            run += v;
        }
    }
}

// ---------------- K4: per-chunk attention; writes bf16 ----------------
__global__ __launch_bounds__(256) void chunk_attn(
    const float* __restrict__ out1, const float* __restrict__ chunkKV,
    const float* __restrict__ chunkKs, ushort* __restrict__ attnBf) {
    __shared__ float Ql[64][68];
    __shared__ float KVl[64][68];
    __shared__ float Sl[64][68];
    __shared__ float Al[64][68];
    __shared__ float sK[64];
    __shared__ float nrm[64];
    const int blk = blockIdx.x;
    const int bh = blk >> 5;
    const int b = bh >> 4, h = bh & 15;
    const int t0 = (blk & 31) * CH_;
    const float* qbase = out1 + (size_t)(b * T_ + t0) * 3072 + h * D_;
    const float* kbase = qbase + C_;
    const float* vbase = qbase + 2 * C_;
    const float* Sbase = chunkKV + (size_t)blk * (M_ * D_);
    const int tid = threadIdx.x;
    for (int i = tid; i < 64 * 16; i += 256) {
        int t = i >> 4, q = (i & 15) * 4;
        *(float4*)&Ql[t][q]  = *(const float4*)(qbase + (size_t)t * 3072 + q);
        *(float4*)&KVl[t][q] = *(const float4*)(kbase + (size_t)t * 3072 + q);
        *(float4*)&Sl[t][q]  = *(const float4*)(Sbase + t * 64 + q);
    }
    if (tid < 64) sK[tid] = chunkKs[(size_t)blk * 64 + tid];
    __syncthreads();
    const int tB = (tid >> 4) * 4, sB = (tid & 15) * 4;
    {
        float a[4][4] = {{0.f}};
#pragma unroll 4
        for (int m = 0; m < 64; ++m) {
            float q0 = Ql[tB + 0][m], q1 = Ql[tB + 1][m], q2 = Ql[tB + 2][m], q3 = Ql[tB + 3][m];
            float k0 = KVl[sB + 0][m], k1 = KVl[sB + 1][m], k2 = KVl[sB + 2][m], k3 = KVl[sB + 3][m];
            a[0][0] += q0 * k0; a[0][1] += q0 * k1; a[0][2] += q0 * k2; a[0][3] += q0 * k3;
            a[1][0] += q1 * k0; a[1][1] += q1 * k1; a[1][2] += q1 * k2; a[1][3] += q1 * k3;
            a[2][0] += q2 * k0; a[2][1] += q2 * k1; a[2][2] += q2 * k2; a[2][3] += q2 * k3;
            a[3][0] += q3 * k0; a[3][1] += q3 * k1; a[3][2] += q3 * k2; a[3][3] += q3 * k3;
        }
#pragma unroll
        for (int i = 0; i < 4; ++i)
#pragma unroll
            for (int j = 0; j < 4; ++j)
                Al[tB + i][sB + j] = (sB + j <= tB + i) ? a[i][j] : 0.f;
    }
    __syncthreads();
    for (int i = tid; i < 64 * 16; i += 256) {
        int t = i >> 4, q = (i & 15) * 4;
        *(float4*)&KVl[t][q] = *(const float4*)(vbase + (size_t)t * 3072 + q);
    }
    if (tid < 64) {
        float s = 0.f;
#pragma unroll 8
        for (int m = 0; m < 64; ++m) s += Ql[tid][m] * sK[m];
        for (int s2 = 0; s2 <= tid; ++s2) s += Al[tid][s2];
        nrm[tid] = s + 1e-6f;
    }
    __syncthreads();
    const int dB = sB;
    float acc[4][4] = {{0.f}};
#pragma unroll 4
    for (int m = 0; m < 64; ++m) {
        float q0 = Ql[tB + 0][m], q1 = Ql[tB + 1][m], q2 = Ql[tB + 2][m], q3 = Ql[tB + 3][m];
        float4 sv = *(const float4*)&Sl[m][dB];
        acc[0][0] += q0 * sv.x; acc[0][1] += q0 * sv.y; acc[0][2] += q0 * sv.z; acc[0][3] += q0 * sv.w;
        acc[1][0] += q1 * sv.x; acc[1][1] += q1 * sv.y; acc[1][2] += q1 * sv.z; acc[1][3] += q1 * sv.w;
        acc[2][0] += q2 * sv.x; acc[2][1] += q2 * sv.y; acc[2][2] += q2 * sv.z; acc[2][3] += q2 * sv.w;
        acc[3][0] += q3 * sv.x; acc[3][1] += q3 * sv.y; acc[3][2] += q3 * sv.z; acc[3][3] += q3 * sv.w;
    }
#pragma unroll 4
    for (int s2 = 0; s2 < 64; ++s2) {
        float a0 = Al[tB + 0][s2], a1 = Al[tB + 1][s2], a2 = Al[tB + 2][s2], a3 = Al[tB + 3][s2];
        float4 vv = *(const float4*)&KVl[s2][dB];
        acc[0][0] += a0 * vv.x; acc[0][1] += a0 * vv.y; acc[0][2] += a0 * vv.z; acc[0][3] += a0 * vv.w;
        acc[1][0] += a1 * vv.x; acc[1][1] += a1 * vv.y; acc[1][2] += a1 * vv.z; acc[1][3] += a1 * vv.w;
        acc[2][0] += a2 * vv.x; acc[2][1] += a2 * vv.y; acc[2][2] += a2 * vv.z; acc[2][3] += a2 * vv.w;
        acc[3][0] += a3 * vv.x; acc[3][1] += a3 * vv.y; acc[3][2] += a3 * vv.z; acc[3][3] += a3 * vv.w;
    }
#pragma unroll
    for (int i = 0; i < 4; ++i) {
        float inv = 1.f / nrm[tB + i];
        ushort4 o = { f2bf(acc[i][0] * inv), f2bf(acc[i][1] * inv),
                      f2bf(acc[i][2] * inv), f2bf(acc[i][3] * inv) };
        *(ushort4*)&attnBf[(size_t)(b * T_ + t0 + tB + i) * C_ + h * D_ + dB] = o;
    }
}

extern "C" void kernel_launch(void* const* d_in, const int* in_sizes, int n_in,
                              void* d_out, int out_size, void* d_ws, size_t ws_size,
                              hipStream_t stream) {
    (void)in_sizes; (void)n_in; (void)out_size; (void)ws_size;
    const float* x    = (const float*)d_in[0];
    const float* Wqkv = (const float*)d_in[1];
    const float* bqkv = (const float*)d_in[2];
    const float* Wout = (const float*)d_in[3];
    const float* bout = (const float*)d_in[4];
    const float* proj = (const float*)d_in[5];
    float* out = (float*)d_out;
    char* ws = (char*)d_ws;

    ushort* Wbt    = (ushort*)ws;                                   // 3072*1024*2  = 6 MB
    ushort* xbf    = (ushort*)(ws + (6 << 20));                     // 4096*1024*2  = 8 MB
    ushort* WoutBf = (ushort*)(ws + (14 << 20));                    // 1024*1024*2  = 2 MB
    ushort* attnBf = (ushort*)(ws + (16 << 20));                    // 4096*1024*2  = 8 MB
    float*  bbig   = (float*)(ws + (24 << 20));                     // 3072*4
    float*  out1   = (float*)(ws + (25 << 20));                     // 4096*3072*4  = 48 MB
    float*  ckv    = (float*)(ws + (73ull << 20));                  // 32*32*4096*4 = 16 MB
    float*  cks    = (float*)(ws + (89ull << 20));                  // 32*32*64*4
    // total ~90 MB

    build_wbigT<<<3072, 256, 0, stream>>>(Wqkv, proj, Wbt);
    build_bbig<<<12, 256, 0, stream>>>(bqkv, proj, bbig);
    cast_f32_bf16<<<4096, 256, 0, stream>>>(x, xbf, 4096 * 1024 / 4);
    cast_f32_bf16<<<1024, 256, 0, stream>>>(Wout, WoutBf, 1024 * 1024 / 4);
    gemm_mfma_bt<<<dim3(24, 32), 256, 0, stream>>>(xbf, Wbt, bbig, out1,
                                                   4096, 3072, 1024, 2048);
    chunk_kv_sums<<<1024, 256, 0, stream>>>(out1, ckv, cks);
    chunk_scan<<<32, 256, 0, stream>>>(ckv, cks);
    chunk_attn<<<1024, 256, 0, stream>>>(out1, ckv, cks, attnBf);
    gemm_mfma_bt<<<dim3(8, 32), 256, 0, stream>>>(attnBf, WoutBf, bout, out,
                                                  4096, 1024, 1024, 0);
}

// Round 3
// 123.662 us; speedup vs baseline: 4.8599x; 1.5547x over previous
//
#include <hip/hip_runtime.h>
#include <cstddef>

#define B_  2
#define T_  2048
#define C_  1024
#define H_  16
#define D_  64
#define M_  64
#define NC_ 32
#define CH_ 64

typedef __attribute__((ext_vector_type(8))) short bf16x8;
typedef __attribute__((ext_vector_type(4))) float f32x4;

__device__ __forceinline__ ushort f2bf(float f) {
    union { float f; unsigned u; } v; v.f = f;
    unsigned r = v.u + 0x7FFF + ((v.u >> 16) & 1);   // RNE
    return (ushort)(r >> 16);
}
__device__ __forceinline__ float bf2f(ushort u) {
    union { unsigned u; float f; } x; x.u = ((unsigned)u) << 16; return x.f;
}

__device__ __forceinline__ void gld_lds16(const ushort* g, ushort* lds) {
    __builtin_amdgcn_global_load_lds(
        (const __attribute__((address_space(1))) unsigned int*)g,
        (__attribute__((address_space(3))) unsigned int*)lds,
        16, 0, 0);
}

// fragment read from a swizzled [64][64] bf16 LDS tile (128B rows, byte ^= (row&7)<<4)
__device__ __forceinline__ bf16x8 frag_ld(const ushort* lds, int row16, int k0, int lane) {
    int r = row16 + (lane & 15);
    int byte = ((k0 * 2) + ((lane >> 4) << 4)) ^ ((r & 7) << 4);
    return *(const bf16x8*)((const char*)lds + r * 128 + byte);
}

// ---------------- build combined projection weights, bf16, [N=3072][K=1024] ----------------
__global__ __launch_bounds__(256) void build_wbigT(const float* __restrict__ Wqkv,
                                                   const float* __restrict__ proj,
                                                   ushort* __restrict__ Wbt) {
    const int j = blockIdx.x;
    const int c0 = threadIdx.x * 4;
    float4 acc = {0.f, 0.f, 0.f, 0.f};
    if (j < 2048) {
        const int sel = j >> 10, hm = j & 1023, h = hm >> 6, m = hm & 63;
        const float* wrow = Wqkv + (size_t)(sel * C_ + h * D_) * C_ + c0;
        const float* p    = proj + (size_t)h * D_ * M_ + m;
#pragma unroll 4
        for (int d = 0; d < D_; ++d) {
            float pv = p[(size_t)d * M_];
            float4 wv = *(const float4*)(wrow + (size_t)d * C_);
            acc.x += wv.x * pv; acc.y += wv.y * pv;
            acc.z += wv.z * pv; acc.w += wv.w * pv;
        }
    } else {
        acc = *(const float4*)(Wqkv + (size_t)j * C_ + c0);
    }
    ushort4 o = { f2bf(acc.x), f2bf(acc.y), f2bf(acc.z), f2bf(acc.w) };
    *(ushort4*)&Wbt[(size_t)j * C_ + c0] = o;
}

__global__ void build_bbig(const float* __restrict__ bqkv,
                           const float* __restrict__ proj,
                           float* __restrict__ bbig) {
    int j = blockIdx.x * blockDim.x + threadIdx.x;
    if (j >= 3072) return;
    if (j < 2048) {
        int sel = j >> 10, hm = j & 1023, h = hm >> 6, m = hm & 63;
        const float* b = bqkv + sel * C_ + h * D_;
        const float* p = proj + (size_t)h * D_ * M_ + m;
        float acc = 0.f;
#pragma unroll 8
        for (int d = 0; d < D_; ++d) acc += b[d] * p[(size_t)d * M_];
        bbig[j] = acc;
    } else {
        bbig[j] = bqkv[j];
    }
}

__global__ void cast_f32_bf16(const float* __restrict__ in, ushort* __restrict__ out, int n4) {
    int i = blockIdx.x * blockDim.x + threadIdx.x;
    if (i >= n4) return;
    float4 v = ((const float4*)in)[i];
    ushort4 o = { f2bf(v.x), f2bf(v.y), f2bf(v.z), f2bf(v.w) };
    ((ushort4*)out)[i] = o;
}

// ---------------- MFMA GEMM (m97 structure), templated output dtype ----------------
template <bool BF16OUT>
__global__ __launch_bounds__(256, 2) void gemm_mfma_bt(
    const ushort* __restrict__ A,    // [M][K] bf16
    const ushort* __restrict__ Bt,   // [N][K] bf16
    const float* __restrict__ bias,  // [N]
    void* __restrict__ Cout,         // [M][N]
    int M, int N, int K, int reluLimit)
{
    __shared__ __align__(16) ushort As[128 * 32];
    __shared__ __align__(16) ushort Bs[128 * 32];
    const int tid  = threadIdx.x;
    const int wave = tid >> 6, lane = tid & 63;
    const int m0 = blockIdx.y * 128, n0 = blockIdx.x * 128;
    const int wr = (wave >> 1) * 64, wc = (wave & 1) * 64;
    f32x4 acc[4][4] = {};

    const int lrow = lane >> 2;
    const int lcol = (lane & 3) * 8;
    ushort* AsB0 = &As[(wave * 2 + 0) * 512];
    ushort* AsB1 = &As[(wave * 2 + 1) * 512];
    ushort* BsB0 = &Bs[(wave * 2 + 0) * 512];
    ushort* BsB1 = &Bs[(wave * 2 + 1) * 512];
    const ushort* Ag0 = A  + (size_t)(m0 + wave * 32 + lrow) * K + lcol;
    const ushort* Ag1 = Ag0 + (size_t)16 * K;
    const ushort* Bg0 = Bt + (size_t)(n0 + wave * 32 + lrow) * K + lcol;
    const ushort* Bg1 = Bg0 + (size_t)16 * K;

    const int frow = lane & 15, fk = (lane >> 4) * 8;

    for (int k0 = 0; k0 < K; k0 += 32) {
        __syncthreads();
        gld_lds16(Ag0 + k0, AsB0);
        gld_lds16(Ag1 + k0, AsB1);
        gld_lds16(Bg0 + k0, BsB0);
        gld_lds16(Bg1 + k0, BsB1);
        __syncthreads();
        bf16x8 af[4], bfr[4];
#pragma unroll
        for (int i = 0; i < 4; ++i)
            af[i] = *(const bf16x8*)&As[(wr + i * 16 + frow) * 32 + fk];
#pragma unroll
        for (int j = 0; j < 4; ++j)
            bfr[j] = *(const bf16x8*)&Bs[(wc + j * 16 + frow) * 32 + fk];
#pragma unroll
        for (int i = 0; i < 4; ++i)
#pragma unroll
            for (int j = 0; j < 4; ++j)
                acc[i][j] = __builtin_amdgcn_mfma_f32_16x16x32_bf16(af[i], bfr[j], acc[i][j], 0, 0, 0);
    }

    const int crow = (lane >> 4) * 4, ccol = lane & 15;
#pragma unroll
    for (int j = 0; j < 4; ++j) {
        int col = n0 + wc + j * 16 + ccol;
        float bv = bias[col];
        bool rl = col < reluLimit;
#pragma unroll
        for (int i = 0; i < 4; ++i) {
#pragma unroll
            for (int r = 0; r < 4; ++r) {
                int row = m0 + wr + i * 16 + crow + r;
                float v = acc[i][j][r] + bv;
                if (rl) v = fmaxf(v, 0.f);
                if (BF16OUT)
                    ((ushort*)Cout)[(size_t)row * N + col] = f2bf(v);
                else
                    ((float*)Cout)[(size_t)row * N + col] = v;
            }
        }
    }
}

// ---------------- chunk_kv: transpose K,V per chunk; St = Vt@Kt^T; sK sums ----------------
// outputs: Vt[blk][64 d][64 t] bf16, St[blk][64 d][64 m] fp32, sks[blk][64 m] fp32
__global__ __launch_bounds__(256) void chunk_kv_mfma(
    const ushort* __restrict__ out1, ushort* __restrict__ VtG,
    float* __restrict__ St, float* __restrict__ sks)
{
    __shared__ unsigned Tl[64 * 76];
    __shared__ ushort Ktb[64 * 64];
    __shared__ ushort Vtb[64 * 64];
    __shared__ float skp[4][64];
    const int blk = blockIdx.x, c = blk & 31, bh = blk >> 5;
    const int b = bh >> 4, h = bh & 15, t0 = c * CH_;
    const int tid = threadIdx.x, wave = tid >> 6, lane = tid & 63;
    const ushort* kg = out1 + (size_t)(b * T_ + t0) * 3072 + C_ + h * D_;
    const ushort* vg = kg + C_;

    // ---- phase A: stage K rows into f32-slot LDS, transposed read -> Ktb + sK partials
#pragma unroll
    for (int it = 0; it < 2; ++it) {
        int i = tid + it * 256, r = i >> 3, sl = i & 7;
        bf16x8 v = *(const bf16x8*)(kg + (size_t)r * 3072 + sl * 8);
        unsigned* dst = &Tl[r * 76 + sl * 8];
        uint4 w0 = { (ushort)v[0], (ushort)v[1], (ushort)v[2], (ushort)v[3] };
        uint4 w1 = { (ushort)v[4], (ushort)v[5], (ushort)v[6], (ushort)v[7] };
        *(uint4*)dst = w0;
        *(uint4*)(dst + 4) = w1;
    }
    __syncthreads();
    {
        int m = tid >> 2, tc = tid & 3;
        bf16x8 va, vb;
        float s = 0.f;
#pragma unroll
        for (int k = 0; k < 8; ++k) {
            ushort u = (ushort)Tl[(tc * 16 + k) * 76 + m];
            va[k] = (short)u; s += bf2f(u);
        }
#pragma unroll
        for (int k = 0; k < 8; ++k) {
            ushort u = (ushort)Tl[(tc * 16 + 8 + k) * 76 + m];
            vb[k] = (short)u; s += bf2f(u);
        }
        skp[tc][m] = s;
        int b0 = (tc * 32) ^ ((m & 7) << 4);
        int b1 = (tc * 32 + 16) ^ ((m & 7) << 4);
        *(bf16x8*)((char*)Ktb + m * 128 + b0) = va;
        *(bf16x8*)((char*)Ktb + m * 128 + b1) = vb;
    }
    __syncthreads();
    // ---- phase B: same for V -> Vtb + global Vt
#pragma unroll
    for (int it = 0; it < 2; ++it) {
        int i = tid + it * 256, r = i >> 3, sl = i & 7;
        bf16x8 v = *(const bf16x8*)(vg + (size_t)r * 3072 + sl * 8);
        unsigned* dst = &Tl[r * 76 + sl * 8];
        uint4 w0 = { (ushort)v[0], (ushort)v[1], (ushort)v[2], (ushort)v[3] };
        uint4 w1 = { (ushort)v[4], (ushort)v[5], (ushort)v[6], (ushort)v[7] };
        *(uint4*)dst = w0;
        *(uint4*)(dst + 4) = w1;
    }
    __syncthreads();
    {
        int d = tid >> 2, tc = tid & 3;
        bf16x8 va, vb;
#pragma unroll
        for (int k = 0; k < 8; ++k) va[k] = (short)(ushort)Tl[(tc * 16 + k) * 76 + d];
#pragma unroll
        for (int k = 0; k < 8; ++k) vb[k] = (short)(ushort)Tl[(tc * 16 + 8 + k) * 76 + d];
        int b0 = (tc * 32) ^ ((d & 7) << 4);
        int b1 = (tc * 32 + 16) ^ ((d & 7) << 4);
        *(bf16x8*)((char*)Vtb + d * 128 + b0) = va;
        *(bf16x8*)((char*)Vtb + d * 128 + b1) = vb;
        ushort* og = VtG + (size_t)blk * 4096 + d * 64 + tc * 16;
        *(bf16x8*)og = va;
        *(bf16x8*)(og + 8) = vb;
    }
    __syncthreads();
    // ---- phase C: St[d][m] = sum_t Vt[d][t]*Kt[m][t]
    const int wr = wave * 16, g = lane >> 4, ccol = lane & 15;
    f32x4 acc[4] = {};
#pragma unroll
    for (int k0 = 0; k0 < 64; k0 += 32) {
        bf16x8 av = frag_ld(Vtb, wr, k0, lane);
#pragma unroll
        for (int j = 0; j < 4; ++j)
            acc[j] = __builtin_amdgcn_mfma_f32_16x16x32_bf16(av, frag_ld(Ktb, j * 16, k0, lane), acc[j], 0, 0, 0);
    }
    float* stg = St + (size_t)blk * 4096;
#pragma unroll
    for (int j = 0; j < 4; ++j)
#pragma unroll
        for (int r = 0; r < 4; ++r)
            stg[(wr + g * 4 + r) * 64 + j * 16 + ccol] = acc[j][r];
    if (tid < 64)
        sks[(size_t)blk * 64 + tid] = skp[0][tid] + skp[1][tid] + skp[2][tid] + skp[3][tid];
}

// ---------------- parallel exclusive chunk-prefix scan ----------------
__global__ __launch_bounds__(256) void chunk_scan2(const float* __restrict__ St,
                                                   const float* __restrict__ sks,
                                                   ushort* __restrict__ Sbf,
                                                   ushort* __restrict__ skb) {
    if (blockIdx.x < 512) {
        int id = blockIdx.x * 256 + threadIdx.x;      // 0..131071
        int bh = id >> 12, e = id & 4095;
        const float* p = St + (size_t)bh * NC_ * 4096 + e;
        ushort* q = Sbf + (size_t)bh * NC_ * 4096 + e;
        float run = 0.f;
        for (int c = 0; c < NC_; ++c) {
            q[(size_t)c * 4096] = f2bf(run);
            run += p[(size_t)c * 4096];
        }
    } else {
        int id2 = (blockIdx.x - 512) * 256 + threadIdx.x;   // 0..2047
        int bh = id2 >> 6, m = id2 & 63;
        const float* p = sks + (size_t)bh * NC_ * 64 + m;
        ushort* q = skb + (size_t)bh * NC_ * 64 + m;
        float run = 0.f;
        for (int c = 0; c < NC_; ++c) {
            q[c * 64] = f2bf(run);
            run += p[c * 64];
        }
    }
}

// ---------------- chunk attention (all-MFMA) ----------------
__global__ __launch_bounds__(256) void chunk_attn_mfma(
    const ushort* __restrict__ out1, const ushort* __restrict__ VtG,
    const ushort* __restrict__ Sbf, const ushort* __restrict__ skb,
    ushort* __restrict__ attnBf)
{
    __shared__ ushort Ql[64 * 64];
    __shared__ ushort Kl[64 * 64];
    __shared__ ushort Vl[64 * 64];   // Vt tile [d][t]
    __shared__ ushort Al[64 * 64];
    __shared__ ushort Sl[80 * 64];   // rows 0-63: S_pre [d][m]; row 64: sK_pre
    const int blk = blockIdx.x, c = blk & 31, bh = blk >> 5;
    const int b = bh >> 4, h = bh & 15, t0 = c * CH_;
    const int tid = threadIdx.x, wave = tid >> 6, lane = tid & 63;
    const ushort* qg  = out1 + (size_t)(b * T_ + t0) * 3072 + h * D_;
    const ushort* kg  = qg + C_;
    const ushort* vtg = VtG + (size_t)blk * 4096;
    const ushort* sbg = Sbf + (size_t)blk * 4096;
#pragma unroll
    for (int it = 0; it < 2; ++it) {
        int i = tid + it * 256, r = i >> 3, sl = i & 7;
        int lo = (sl * 16) ^ ((r & 7) << 4);
        *(bf16x8*)((char*)Ql + r * 128 + lo) = *(const bf16x8*)(qg + (size_t)r * 3072 + sl * 8);
        *(bf16x8*)((char*)Kl + r * 128 + lo) = *(const bf16x8*)(kg + (size_t)r * 3072 + sl * 8);
        *(bf16x8*)((char*)Vl + r * 128 + lo) = *(const bf16x8*)(vtg + r * 64 + sl * 8);
        *(bf16x8*)((char*)Sl + r * 128 + lo) = *(const bf16x8*)(sbg + r * 64 + sl * 8);
    }
    if (tid < 8)
        *(bf16x8*)((char*)Sl + 64 * 128 + tid * 16) = *(const bf16x8*)(skb + (size_t)blk * 64 + tid * 8);
    __syncthreads();

    const int wr = wave * 16, g = lane >> 4, ccol = lane & 15;
    // QK^T: 16 t-rows per wave, all 64 s-cols
    f32x4 accA[4] = {};
#pragma unroll
    for (int k0 = 0; k0 < 64; k0 += 32) {
        bf16x8 aq = frag_ld(Ql, wr, k0, lane);
#pragma unroll
        for (int j = 0; j < 4; ++j)
            accA[j] = __builtin_amdgcn_mfma_f32_16x16x32_bf16(aq, frag_ld(Kl, j * 16, k0, lane), accA[j], 0, 0, 0);
    }
    // mask + fp32 rowsum + bf16 A to (wave-local) LDS
    float rsum[4] = {0.f, 0.f, 0.f, 0.f};
#pragma unroll
    for (int j = 0; j < 4; ++j) {
#pragma unroll
        for (int r = 0; r < 4; ++r) {
            int tl = wr + g * 4 + r, sl2 = j * 16 + ccol;
            float v = (sl2 <= tl) ? accA[j][r] : 0.f;
            rsum[r] += v;
            *(ushort*)((char*)Al + tl * 128 + ((sl2 * 2) ^ ((tl & 7) << 4))) = f2bf(v);
        }
    }
#pragma unroll
    for (int r = 0; r < 4; ++r) {
        rsum[r] += __shfl_xor(rsum[r], 1);
        rsum[r] += __shfl_xor(rsum[r], 2);
        rsum[r] += __shfl_xor(rsum[r], 4);
        rsum[r] += __shfl_xor(rsum[r], 8);
    }
    // PV (A@Vt^T) + QS (Q@S_pre^T) + norm column (Q@sK_pre)
    f32x4 accC[4] = {};
    f32x4 accE = {};
#pragma unroll
    for (int k0 = 0; k0 < 64; k0 += 32) {
        bf16x8 aa = frag_ld(Al, wr, k0, lane);   // own wave's rows only
#pragma unroll
        for (int j = 0; j < 4; ++j)
            accC[j] = __builtin_amdgcn_mfma_f32_16x16x32_bf16(aa, frag_ld(Vl, j * 16, k0, lane), accC[j], 0, 0, 0);
    }
#pragma unroll
    for (int k0 = 0; k0 < 64; k0 += 32) {
        bf16x8 aq = frag_ld(Ql, wr, k0, lane);
#pragma unroll
        for (int j = 0; j < 4; ++j)
            accC[j] = __builtin_amdgcn_mfma_f32_16x16x32_bf16(aq, frag_ld(Sl, j * 16, k0, lane), accC[j], 0, 0, 0);
        accE = __builtin_amdgcn_mfma_f32_16x16x32_bf16(aq, frag_ld(Sl, 64, k0, lane), accE, 0, 0, 0);
    }
    // epilogue
    ushort* og = attnBf + (size_t)(b * T_ + t0) * C_ + h * D_;
#pragma unroll
    for (int r = 0; r < 4; ++r) {
        float nq = __shfl(accE[r], (lane & 48));          // lane with ccol==0 in group
        float inv = 1.f / (nq + rsum[r] + 1e-6f);
        int tl = wr + g * 4 + r;
#pragma unroll
        for (int j = 0; j < 4; ++j)
            og[(size_t)tl * C_ + j * 16 + ccol] = f2bf(accC[j][r] * inv);
    }
}

extern "C" void kernel_launch(void* const* d_in, const int* in_sizes, int n_in,
                              void* d_out, int out_size, void* d_ws, size_t ws_size,
                              hipStream_t stream) {
    (void)in_sizes; (void)n_in; (void)out_size; (void)ws_size;
    const float* x    = (const float*)d_in[0];
    const float* Wqkv = (const float*)d_in[1];
    const float* bqkv = (const float*)d_in[2];
    const float* Wout = (const float*)d_in[3];
    const float* bout = (const float*)d_in[4];
    const float* proj = (const float*)d_in[5];
    float* out = (float*)d_out;
    char* ws = (char*)d_ws;

    ushort* Wbt    = (ushort*)(ws);                 // 6 MB
    ushort* xbf    = (ushort*)(ws + (6ull  << 20)); // 8 MB
    ushort* WoutBf = (ushort*)(ws + (14ull << 20)); // 2 MB
    ushort* attnBf = (ushort*)(ws + (16ull << 20)); // 8 MB
    float*  bbig   = (float*) (ws + (24ull << 20)); // 12 KB
    ushort* out1   = (ushort*)(ws + (25ull << 20)); // 24 MB (bf16 q'|k'|v)
    ushort* VtG    = (ushort*)(ws + (49ull << 20)); // 8 MB
    float*  St     = (float*) (ws + (57ull << 20)); // 16 MB
    ushort* Sbf    = (ushort*)(ws + (73ull << 20)); // 8 MB
    float*  sks    = (float*) (ws + (81ull << 20)); // 256 KB
    ushort* skb    = (ushort*)(ws + (82ull << 20)); // 128 KB

    build_wbigT<<<3072, 256, 0, stream>>>(Wqkv, proj, Wbt);
    build_bbig<<<12, 256, 0, stream>>>(bqkv, proj, bbig);
    cast_f32_bf16<<<4096, 256, 0, stream>>>(x, xbf, 4096 * 1024 / 4);
    cast_f32_bf16<<<1024, 256, 0, stream>>>(Wout, WoutBf, 1024 * 1024 / 4);
    gemm_mfma_bt<true><<<dim3(24, 32), 256, 0, stream>>>(xbf, Wbt, bbig, out1,
                                                         4096, 3072, 1024, 2048);
    chunk_kv_mfma<<<1024, 256, 0, stream>>>(out1, VtG, St, sks);
    chunk_scan2<<<520, 256, 0, stream>>>(St, sks, Sbf, skb);
    chunk_attn_mfma<<<1024, 256, 0, stream>>>(out1, VtG, Sbf, skb, attnBf);
    gemm_mfma_bt<false><<<dim3(8, 32), 256, 0, stream>>>(attnBf, WoutBf, bout, out,
                                                         4096, 1024, 1024, 0);
}

// Round 5
// 121.231 us; speedup vs baseline: 4.9573x; 1.0201x over previous
//
#include <hip/hip_runtime.h>
#include <cstddef>

#define B_  2
#define T_  2048
#define C_  1024
#define H_  16
#define D_  64
#define M_  64
#define NC_ 32
#define CH_ 64

typedef __attribute__((ext_vector_type(8))) short bf16x8;
typedef __attribute__((ext_vector_type(4))) float f32x4;

__device__ __forceinline__ ushort f2bf(float f) {
    union { float f; unsigned u; } v; v.f = f;
    unsigned r = v.u + 0x7FFF + ((v.u >> 16) & 1);   // RNE
    return (ushort)(r >> 16);
}
__device__ __forceinline__ float bf2f(ushort u) {
    union { unsigned u; float f; } x; x.u = ((unsigned)u) << 16; return x.f;
}

__device__ __forceinline__ void gld_lds16(const ushort* g, ushort* lds) {
    __builtin_amdgcn_global_load_lds(
        (const __attribute__((address_space(1))) unsigned int*)g,
        (__attribute__((address_space(3))) unsigned int*)lds,
        16, 0, 0);
}

// fragment read from a swizzled [R][64] bf16 LDS tile (128B rows, byte ^= (row&7)<<4)
__device__ __forceinline__ bf16x8 frag_ld(const ushort* lds, int row16, int k0, int lane) {
    int r = row16 + (lane & 15);
    int byte = ((k0 * 2) + ((lane >> 4) << 4)) ^ ((r & 7) << 4);
    return *(const bf16x8*)((const char*)lds + r * 128 + byte);
}

#define VMCNT(n) asm volatile("s_waitcnt vmcnt(" #n ")" ::: "memory")
#define BAR() do { __builtin_amdgcn_s_barrier(); __builtin_amdgcn_sched_barrier(0); } while (0)

// ---------------- build combined projection weights, bf16, [N=3072][K=1024] ----------------
__global__ __launch_bounds__(256) void build_wbigT(const float* __restrict__ Wqkv,
                                                   const float* __restrict__ proj,
                                                   ushort* __restrict__ Wbt) {
    const int j = blockIdx.x;
    const int c0 = threadIdx.x * 4;
    float4 acc = {0.f, 0.f, 0.f, 0.f};
    if (j < 2048) {
        const int sel = j >> 10, hm = j & 1023, h = hm >> 6, m = hm & 63;
        const float* wrow = Wqkv + (size_t)(sel * C_ + h * D_) * C_ + c0;
        const float* p    = proj + (size_t)h * D_ * M_ + m;
#pragma unroll 4
        for (int d = 0; d < D_; ++d) {
            float pv = p[(size_t)d * M_];
            float4 wv = *(const float4*)(wrow + (size_t)d * C_);
            acc.x += wv.x * pv; acc.y += wv.y * pv;
            acc.z += wv.z * pv; acc.w += wv.w * pv;
        }
    } else {
        acc = *(const float4*)(Wqkv + (size_t)j * C_ + c0);
    }
    ushort4 o = { f2bf(acc.x), f2bf(acc.y), f2bf(acc.z), f2bf(acc.w) };
    *(ushort4*)&Wbt[(size_t)j * C_ + c0] = o;
}

__global__ void build_bbig(const float* __restrict__ bqkv,
                           const float* __restrict__ proj,
                           float* __restrict__ bbig) {
    int j = blockIdx.x * blockDim.x + threadIdx.x;
    if (j >= 3072) return;
    if (j < 2048) {
        int sel = j >> 10, hm = j & 1023, h = hm >> 6, m = hm & 63;
        const float* b = bqkv + sel * C_ + h * D_;
        const float* p = proj + (size_t)h * D_ * M_ + m;
        float acc = 0.f;
#pragma unroll 8
        for (int d = 0; d < D_; ++d) acc += b[d] * p[(size_t)d * M_];
        bbig[j] = acc;
    } else {
        bbig[j] = bqkv[j];
    }
}

__global__ void cast_f32_bf16(const float* __restrict__ in, ushort* __restrict__ out, int n4) {
    int i = blockIdx.x * blockDim.x + threadIdx.x;
    if (i >= n4) return;
    float4 v = ((const float4*)in)[i];
    ushort4 o = { f2bf(v.x), f2bf(v.y), f2bf(v.z), f2bf(v.w) };
    ((ushort4*)out)[i] = o;
}

// ================= 8-phase pipelined GEMM: C = relu?(A[M][K] @ Bt[N][K]^T + bias) =================
// BM=128, BN=384, BK=64, 512 threads (8 waves, 2M x 4N), per-wave 64x96.
// LDS: A[2][128][64] (16KB x2) + B[2][384][64] (48KB x2) = 128KB, XOR16 row-swizzled.
// Per-thread stage work: 4 gld_lds16 in G0, 4 in G1 (=8 total = 64KB/tile/512thr).
// Waits (steady): vmcnt(4)/(5)/(4)/none; drain tile: (4)/(1)/(0)/none.

__device__ __forceinline__ void stage_G0(const ushort* __restrict__ Ag, const ushort* __restrict__ Bg,
                                         ushort* Abuf, ushort* Bbuf,
                                         int m0, int n0, int K, int kcol, int w, int lane) {
    const int l8 = lane >> 3, lc = (lane & 7) * 8;   // lc in ushort units
#pragma unroll
    for (int i = 0; i < 4; ++i) {
        int c = w * 4 + i;
        if (c < 8) {
            int fr = (c < 4) ? c * 8 : 64 + (c - 4) * 8;
            int r = fr + l8;
            int cs = lc ^ ((r & 7) << 3);
            gld_lds16(Ag + (size_t)(m0 + r) * K + kcol + cs, Abuf + fr * 64);
        } else {
            int cb = c - 8, g = cb / 6, k8 = cb - g * 6;
            int fr = g * 96 + k8 * 8;
            int r = fr + l8;
            int cs = lc ^ ((r & 7) << 3);
            gld_lds16(Bg + (size_t)(n0 + r) * K + kcol + cs, Bbuf + fr * 64);
        }
    }
}

__device__ __forceinline__ void stage_G1(const ushort* __restrict__ Ag, const ushort* __restrict__ Bg,
                                         ushort* Abuf, ushort* Bbuf,
                                         int m0, int n0, int K, int kcol, int w, int lane) {
    const int l8 = lane >> 3, lc = (lane & 7) * 8;
#pragma unroll
    for (int i = 0; i < 3; ++i) {                    // B first (needed at phase 1)
        int cb = w * 3 + i, g = cb / 6, k8 = cb - g * 6;
        int fr = g * 96 + 48 + k8 * 8;
        int r = fr + l8;
        int cs = lc ^ ((r & 7) << 3);
        gld_lds16(Bg + (size_t)(n0 + r) * K + kcol + cs, Bbuf + fr * 64);
    }
    {                                                // A half1 (needed at phase 2)
        int fr = (w < 4) ? 32 + w * 8 : 96 + (w - 4) * 8;
        int r = fr + l8;
        int cs = lc ^ ((r & 7) << 3);
        gld_lds16(Ag + (size_t)(m0 + r) * K + kcol + cs, Abuf + fr * 64);
    }
}

__device__ __forceinline__ void phase_mfma(const ushort* Abuf, const ushort* Bbuf,
                                           f32x4 (&acc)[4][6], int wr, int wc, int lane,
                                           int Mh, int Nh) {
    bf16x8 a[2][2], b[3][2];
#pragma unroll
    for (int i = 0; i < 2; ++i)
#pragma unroll
        for (int ks = 0; ks < 2; ++ks)
            a[i][ks] = frag_ld(Abuf, wr + Mh * 32 + i * 16, ks * 32, lane);
#pragma unroll
    for (int j = 0; j < 3; ++j)
#pragma unroll
        for (int ks = 0; ks < 2; ++ks)
            b[j][ks] = frag_ld(Bbuf, wc + Nh * 48 + j * 16, ks * 32, lane);
    __builtin_amdgcn_s_setprio(1);
#pragma unroll
    for (int ks = 0; ks < 2; ++ks)
#pragma unroll
        for (int i = 0; i < 2; ++i)
#pragma unroll
            for (int j = 0; j < 3; ++j)
                acc[Mh * 2 + i][Nh * 3 + j] = __builtin_amdgcn_mfma_f32_16x16x32_bf16(
                    a[i][ks], b[j][ks], acc[Mh * 2 + i][Nh * 3 + j], 0, 0, 0);
    __builtin_amdgcn_s_setprio(0);
}

__global__ __launch_bounds__(512) void gemm_8phase(
    const ushort* __restrict__ A,    // [M][K] bf16
    const ushort* __restrict__ Bt,   // [N][K] bf16
    const float* __restrict__ bias,
    ushort* __restrict__ Cout,       // [M][N] bf16
    int M, int N, int K, int reluLimit)
{
    __shared__ __align__(16) ushort lds[65536];      // 128 KiB

    const int tid = threadIdx.x, w = tid >> 6, lane = tid & 63;
    const int m0 = blockIdx.y * 128, n0 = blockIdx.x * 384;
    const int wr = (w >> 2) * 64, wc = (w & 3) * 96;
    f32x4 acc[4][6] = {};
    const int NT = K / 64;

    // prologue: fully stage K-tile 0 into buffer 0
    stage_G0(A, Bt, lds, lds + 16384, m0, n0, K, 0, w, lane);
    stage_G1(A, Bt, lds, lds + 16384, m0, n0, K, 0, w, lane);

    for (int kt = 0; kt < NT - 1; ++kt) {
        const int p = kt & 1;
        ushort* Acur = lds + p * 8192;
        ushort* Anxt = lds + (p ^ 1) * 8192;
        ushort* Bcur = lds + 16384 + p * 24576;
        ushort* Bnxt = lds + 16384 + (p ^ 1) * 24576;
        const int kc1 = (kt + 1) * 64;
        // phase 0: (Mh0,Nh0) — needs kt.G0
        VMCNT(4); BAR();
        stage_G0(A, Bt, Anxt, Bnxt, m0, n0, K, kc1, w, lane);
        phase_mfma(Acur, Bcur, acc, wr, wc, lane, 0, 0);
        // phase 1: (Mh0,Nh1) — needs kt.G1 B-part
        VMCNT(5); BAR();
        phase_mfma(Acur, Bcur, acc, wr, wc, lane, 0, 1);
        // phase 2: (Mh1,Nh0) — needs kt.G1 A-part
        VMCNT(4); BAR();
        stage_G1(A, Bt, Anxt, Bnxt, m0, n0, K, kc1, w, lane);
        phase_mfma(Acur, Bcur, acc, wr, wc, lane, 1, 0);
        // phase 3: (Mh1,Nh1) — no new data, no barrier
        phase_mfma(Acur, Bcur, acc, wr, wc, lane, 1, 1);
    }
    {   // drain tile
        const int p = (NT - 1) & 1;
        ushort* Acur = lds + p * 8192;
        ushort* Bcur = lds + 16384 + p * 24576;
        VMCNT(4); BAR();
        phase_mfma(Acur, Bcur, acc, wr, wc, lane, 0, 0);
        VMCNT(1); BAR();
        phase_mfma(Acur, Bcur, acc, wr, wc, lane, 0, 1);
        VMCNT(0); BAR();
        phase_mfma(Acur, Bcur, acc, wr, wc, lane, 1, 0);
        phase_mfma(Acur, Bcur, acc, wr, wc, lane, 1, 1);
    }

    // epilogue: D col=lane&15, row=(lane>>4)*4+r
    const int crow = (lane >> 4) * 4, ccol = lane & 15;
#pragma unroll
    for (int nj = 0; nj < 6; ++nj) {
        int col = n0 + wc + nj * 16 + ccol;
        float bv = bias[col];
        bool rl = col < reluLimit;
#pragma unroll
        for (int mi = 0; mi < 4; ++mi) {
#pragma unroll
            for (int rr = 0; rr < 4; ++rr) {
                int row = m0 + wr + mi * 16 + crow + rr;
                float v = acc[mi][nj][rr] + bv;
                if (rl) v = fmaxf(v, 0.f);
                Cout[(size_t)row * N + col] = f2bf(v);
            }
        }
    }
}

// ---------------- m97-structure MFMA GEMM (fp32 out) for GEMM2 ----------------
__global__ __launch_bounds__(256, 2) void gemm_mfma_bt(
    const ushort* __restrict__ A, const ushort* __restrict__ Bt,
    const float* __restrict__ bias, float* __restrict__ Cmat,
    int M, int N, int K, int reluLimit)
{
    __shared__ __align__(16) ushort As[128 * 32];
    __shared__ __align__(16) ushort Bs[128 * 32];
    const int tid  = threadIdx.x;
    const int wave = tid >> 6, lane = tid & 63;
    const int m0 = blockIdx.y * 128, n0 = blockIdx.x * 128;
    const int wr = (wave >> 1) * 64, wc = (wave & 1) * 64;
    f32x4 acc[4][4] = {};

    const int lrow = lane >> 2;
    const int lcol = (lane & 3) * 8;
    ushort* AsB0 = &As[(wave * 2 + 0) * 512];
    ushort* AsB1 = &As[(wave * 2 + 1) * 512];
    ushort* BsB0 = &Bs[(wave * 2 + 0) * 512];
    ushort* BsB1 = &Bs[(wave * 2 + 1) * 512];
    const ushort* Ag0 = A  + (size_t)(m0 + wave * 32 + lrow) * K + lcol;
    const ushort* Ag1 = Ag0 + (size_t)16 * K;
    const ushort* Bg0 = Bt + (size_t)(n0 + wave * 32 + lrow) * K + lcol;
    const ushort* Bg1 = Bg0 + (size_t)16 * K;

    const int frow = lane & 15, fk = (lane >> 4) * 8;

    for (int k0 = 0; k0 < K; k0 += 32) {
        __syncthreads();
        gld_lds16(Ag0 + k0, AsB0);
        gld_lds16(Ag1 + k0, AsB1);
        gld_lds16(Bg0 + k0, BsB0);
        gld_lds16(Bg1 + k0, BsB1);
        __syncthreads();
        bf16x8 af[4], bfr[4];
#pragma unroll
        for (int i = 0; i < 4; ++i)
            af[i] = *(const bf16x8*)&As[(wr + i * 16 + frow) * 32 + fk];
#pragma unroll
        for (int j = 0; j < 4; ++j)
            bfr[j] = *(const bf16x8*)&Bs[(wc + j * 16 + frow) * 32 + fk];
#pragma unroll
        for (int i = 0; i < 4; ++i)
#pragma unroll
            for (int j = 0; j < 4; ++j)
                acc[i][j] = __builtin_amdgcn_mfma_f32_16x16x32_bf16(af[i], bfr[j], acc[i][j], 0, 0, 0);
    }

    const int crow = (lane >> 4) * 4, ccol = lane & 15;
#pragma unroll
    for (int j = 0; j < 4; ++j) {
        int col = n0 + wc + j * 16 + ccol;
        float bv = bias[col];
        bool rl = col < reluLimit;
#pragma unroll
        for (int i = 0; i < 4; ++i) {
#pragma unroll
            for (int r = 0; r < 4; ++r) {
                int row = m0 + wr + i * 16 + crow + r;
                float v = acc[i][j][r] + bv;
                if (rl) v = fmaxf(v, 0.f);
                Cmat[(size_t)row * N + col] = v;
            }
        }
    }
}

// ---------------- chunk_kv: transpose K,V per chunk; St = Vt@Kt^T; sK sums ----------------
__global__ __launch_bounds__(256) void chunk_kv_mfma(
    const ushort* __restrict__ out1, ushort* __restrict__ VtG,
    float* __restrict__ St, float* __restrict__ sks)
{
    __shared__ unsigned Tl[64 * 76];
    __shared__ ushort Ktb[64 * 64];
    __shared__ ushort Vtb[64 * 64];
    __shared__ float skp[4][64];
    const int blk = blockIdx.x, c = blk & 31, bh = blk >> 5;
    const int b = bh >> 4, h = bh & 15, t0 = c * CH_;
    const int tid = threadIdx.x, wave = tid >> 6, lane = tid & 63;
    const ushort* kg = out1 + (size_t)(b * T_ + t0) * 3072 + C_ + h * D_;
    const ushort* vg = kg + C_;

#pragma unroll
    for (int it = 0; it < 2; ++it) {
        int i = tid + it * 256, r = i >> 3, sl = i & 7;
        bf16x8 v = *(const bf16x8*)(kg + (size_t)r * 3072 + sl * 8);
        unsigned* dst = &Tl[r * 76 + sl * 8];
        uint4 w0 = { (ushort)v[0], (ushort)v[1], (ushort)v[2], (ushort)v[3] };
        uint4 w1 = { (ushort)v[4], (ushort)v[5], (ushort)v[6], (ushort)v[7] };
        *(uint4*)dst = w0;
        *(uint4*)(dst + 4) = w1;
    }
    __syncthreads();
    {
        int m = tid >> 2, tc = tid & 3;
        bf16x8 va, vb;
        float s = 0.f;
#pragma unroll
        for (int k = 0; k < 8; ++k) {
            ushort u = (ushort)Tl[(tc * 16 + k) * 76 + m];
            va[k] = (short)u; s += bf2f(u);
        }
#pragma unroll
        for (int k = 0; k < 8; ++k) {
            ushort u = (ushort)Tl[(tc * 16 + 8 + k) * 76 + m];
            vb[k] = (short)u; s += bf2f(u);
        }
        skp[tc][m] = s;
        int b0 = (tc * 32) ^ ((m & 7) << 4);
        int b1 = (tc * 32 + 16) ^ ((m & 7) << 4);
        *(bf16x8*)((char*)Ktb + m * 128 + b0) = va;
        *(bf16x8*)((char*)Ktb + m * 128 + b1) = vb;
    }
    __syncthreads();
#pragma unroll
    for (int it = 0; it < 2; ++it) {
        int i = tid + it * 256, r = i >> 3, sl = i & 7;
        bf16x8 v = *(const bf16x8*)(vg + (size_t)r * 3072 + sl * 8);
        unsigned* dst = &Tl[r * 76 + sl * 8];
        uint4 w0 = { (ushort)v[0], (ushort)v[1], (ushort)v[2], (ushort)v[3] };
        uint4 w1 = { (ushort)v[4], (ushort)v[5], (ushort)v[6], (ushort)v[7] };
        *(uint4*)dst = w0;
        *(uint4*)(dst + 4) = w1;
    }
    __syncthreads();
    {
        int d = tid >> 2, tc = tid & 3;
        bf16x8 va, vb;
#pragma unroll
        for (int k = 0; k < 8; ++k) va[k] = (short)(ushort)Tl[(tc * 16 + k) * 76 + d];
#pragma unroll
        for (int k = 0; k < 8; ++k) vb[k] = (short)(ushort)Tl[(tc * 16 + 8 + k) * 76 + d];
        int b0 = (tc * 32) ^ ((d & 7) << 4);
        int b1 = (tc * 32 + 16) ^ ((d & 7) << 4);
        *(bf16x8*)((char*)Vtb + d * 128 + b0) = va;
        *(bf16x8*)((char*)Vtb + d * 128 + b1) = vb;
        ushort* og = VtG + (size_t)blk * 4096 + d * 64 + tc * 16;
        *(bf16x8*)og = va;
        *(bf16x8*)(og + 8) = vb;
    }
    __syncthreads();
    const int wr = wave * 16, g = lane >> 4, ccol = lane & 15;
    f32x4 acc[4] = {};
#pragma unroll
    for (int k0 = 0; k0 < 64; k0 += 32) {
        bf16x8 av = frag_ld(Vtb, wr, k0, lane);
#pragma unroll
        for (int j = 0; j < 4; ++j)
            acc[j] = __builtin_amdgcn_mfma_f32_16x16x32_bf16(av, frag_ld(Ktb, j * 16, k0, lane), acc[j], 0, 0, 0);
    }
    float* stg = St + (size_t)blk * 4096;
#pragma unroll
    for (int j = 0; j < 4; ++j)
#pragma unroll
        for (int r = 0; r < 4; ++r)
            stg[(wr + g * 4 + r) * 64 + j * 16 + ccol] = acc[j][r];
    if (tid < 64)
        sks[(size_t)blk * 64 + tid] = skp[0][tid] + skp[1][tid] + skp[2][tid] + skp[3][tid];
}

// ---------------- parallel exclusive chunk-prefix scan ----------------
__global__ __launch_bounds__(256) void chunk_scan2(const float* __restrict__ St,
                                                   const float* __restrict__ sks,
                                                   ushort* __restrict__ Sbf,
                                                   ushort* __restrict__ skb) {
    if (blockIdx.x < 512) {
        int id = blockIdx.x * 256 + threadIdx.x;
        int bh = id >> 12, e = id & 4095;
        const float* p = St + (size_t)bh * NC_ * 4096 + e;
        ushort* q = Sbf + (size_t)bh * NC_ * 4096 + e;
        float run = 0.f;
        for (int c = 0; c < NC_; ++c) {
            q[(size_t)c * 4096] = f2bf(run);
            run += p[(size_t)c * 4096];
        }
    } else {
        int id2 = (blockIdx.x - 512) * 256 + threadIdx.x;
        int bh = id2 >> 6, m = id2 & 63;
        const float* p = sks + (size_t)bh * NC_ * 64 + m;
        ushort* q = skb + (size_t)bh * NC_ * 64 + m;
        float run = 0.f;
        for (int c = 0; c < NC_; ++c) {
            q[c * 64] = f2bf(run);
            run += p[c * 64];
        }
    }
}

// ---------------- chunk attention (all-MFMA) ----------------
__global__ __launch_bounds__(256) void chunk_attn_mfma(
    const ushort* __restrict__ out1, const ushort* __restrict__ VtG,
    const ushort* __restrict__ Sbf, const ushort* __restrict__ skb,
    ushort* __restrict__ attnBf)
{
    __shared__ ushort Ql[64 * 64];
    __shared__ ushort Kl[64 * 64];
    __shared__ ushort Vl[64 * 64];
    __shared__ ushort Al[64 * 64];
    __shared__ ushort Sl[80 * 64];
    const int blk = blockIdx.x, c = blk & 31, bh = blk >> 5;
    const int b = bh >> 4, h = bh & 15, t0 = c * CH_;
    const int tid = threadIdx.x, wave = tid >> 6, lane = tid & 63;
    const ushort* qg  = out1 + (size_t)(b * T_ + t0) * 3072 + h * D_;
    const ushort* kg  = qg + C_;
    const ushort* vtg = VtG + (size_t)blk * 4096;
    const ushort* sbg = Sbf + (size_t)blk * 4096;
#pragma unroll
    for (int it = 0; it < 2; ++it) {
        int i = tid + it * 256, r = i >> 3, sl = i & 7;
        int lo = (sl * 16) ^ ((r & 7) << 4);
        *(bf16x8*)((char*)Ql + r * 128 + lo) = *(const bf16x8*)(qg + (size_t)r * 3072 + sl * 8);
        *(bf16x8*)((char*)Kl + r * 128 + lo) = *(const bf16x8*)(kg + (size_t)r * 3072 + sl * 8);
        *(bf16x8*)((char*)Vl + r * 128 + lo) = *(const bf16x8*)(vtg + r * 64 + sl * 8);
        *(bf16x8*)((char*)Sl + r * 128 + lo) = *(const bf16x8*)(sbg + r * 64 + sl * 8);
    }
    if (tid < 8)
        *(bf16x8*)((char*)Sl + 64 * 128 + tid * 16) = *(const bf16x8*)(skb + (size_t)blk * 64 + tid * 8);
    __syncthreads();

    const int wr = wave * 16, g = lane >> 4, ccol = lane & 15;
    f32x4 accA[4] = {};
#pragma unroll
    for (int k0 = 0; k0 < 64; k0 += 32) {
        bf16x8 aq = frag_ld(Ql, wr, k0, lane);
#pragma unroll
        for (int j = 0; j < 4; ++j)
            accA[j] = __builtin_amdgcn_mfma_f32_16x16x32_bf16(aq, frag_ld(Kl, j * 16, k0, lane), accA[j], 0, 0, 0);
    }
    float rsum[4] = {0.f, 0.f, 0.f, 0.f};
#pragma unroll
    for (int j = 0; j < 4; ++j) {
#pragma unroll
        for (int r = 0; r < 4; ++r) {
            int tl = wr + g * 4 + r, sl2 = j * 16 + ccol;
            float v = (sl2 <= tl) ? accA[j][r] : 0.f;
            rsum[r] += v;
            *(ushort*)((char*)Al + tl * 128 + ((sl2 * 2) ^ ((tl & 7) << 4))) = f2bf(v);
        }
    }
#pragma unroll
    for (int r = 0; r < 4; ++r) {
        rsum[r] += __shfl_xor(rsum[r], 1);
        rsum[r] += __shfl_xor(rsum[r], 2);
        rsum[r] += __shfl_xor(rsum[r], 4);
        rsum[r] += __shfl_xor(rsum[r], 8);
    }
    f32x4 accC[4] = {};
    f32x4 accE = {};
#pragma unroll
    for (int k0 = 0; k0 < 64; k0 += 32) {
        bf16x8 aa = frag_ld(Al, wr, k0, lane);
#pragma unroll
        for (int j = 0; j < 4; ++j)
            accC[j] = __builtin_amdgcn_mfma_f32_16x16x32_bf16(aa, frag_ld(Vl, j * 16, k0, lane), accC[j], 0, 0, 0);
    }
#pragma unroll
    for (int k0 = 0; k0 < 64; k0 += 32) {
        bf16x8 aq = frag_ld(Ql, wr, k0, lane);
#pragma unroll
        for (int j = 0; j < 4; ++j)
            accC[j] = __builtin_amdgcn_mfma_f32_16x16x32_bf16(aq, frag_ld(Sl, j * 16, k0, lane), accC[j], 0, 0, 0);
        accE = __builtin_amdgcn_mfma_f32_16x16x32_bf16(aq, frag_ld(Sl, 64, k0, lane), accE, 0, 0, 0);
    }
    ushort* og = attnBf + (size_t)(b * T_ + t0) * C_ + h * D_;
#pragma unroll
    for (int r = 0; r < 4; ++r) {
        float nq = __shfl(accE[r], (lane & 48));
        float inv = 1.f / (nq + rsum[r] + 1e-6f);
        int tl = wr + g * 4 + r;
#pragma unroll
        for (int j = 0; j < 4; ++j)
            og[(size_t)tl * C_ + j * 16 + ccol] = f2bf(accC[j][r] * inv);
    }
}

extern "C" void kernel_launch(void* const* d_in, const int* in_sizes, int n_in,
                              void* d_out, int out_size, void* d_ws, size_t ws_size,
                              hipStream_t stream) {
    (void)in_sizes; (void)n_in; (void)out_size; (void)ws_size;
    const float* x    = (const float*)d_in[0];
    const float* Wqkv = (const float*)d_in[1];
    const float* bqkv = (const float*)d_in[2];
    const float* Wout = (const float*)d_in[3];
    const float* bout = (const float*)d_in[4];
    const float* proj = (const float*)d_in[5];
    float* out = (float*)d_out;
    char* ws = (char*)d_ws;

    ushort* Wbt    = (ushort*)(ws);                 // 6 MB
    ushort* xbf    = (ushort*)(ws + (6ull  << 20)); // 8 MB
    ushort* WoutBf = (ushort*)(ws + (14ull << 20)); // 2 MB
    ushort* attnBf = (ushort*)(ws + (16ull << 20)); // 8 MB
    float*  bbig   = (float*) (ws + (24ull << 20)); // 12 KB
    ushort* out1   = (ushort*)(ws + (25ull << 20)); // 24 MB (bf16 q'|k'|v)
    ushort* VtG    = (ushort*)(ws + (49ull << 20)); // 8 MB
    float*  St     = (float*) (ws + (57ull << 20)); // 16 MB
    ushort* Sbf    = (ushort*)(ws + (73ull << 20)); // 8 MB
    float*  sks    = (float*) (ws + (81ull << 20)); // 256 KB
    ushort* skb    = (ushort*)(ws + (82ull << 20)); // 128 KB

    build_wbigT<<<3072, 256, 0, stream>>>(Wqkv, proj, Wbt);
    build_bbig<<<12, 256, 0, stream>>>(bqkv, proj, bbig);
    cast_f32_bf16<<<4096, 256, 0, stream>>>(x, xbf, 4096 * 1024 / 4);
    cast_f32_bf16<<<1024, 256, 0, stream>>>(Wout, WoutBf, 1024 * 1024 / 4);
    gemm_8phase<<<dim3(8, 32), 512, 0, stream>>>(xbf, Wbt, bbig, out1,
                                                 4096, 3072, 1024, 2048);
    chunk_kv_mfma<<<1024, 256, 0, stream>>>(out1, VtG, St, sks);
    chunk_scan2<<<520, 256, 0, stream>>>(St, sks, Sbf, skb);
    chunk_attn_mfma<<<1024, 256, 0, stream>>>(out1, VtG, Sbf, skb, attnBf);
    gemm_mfma_bt<<<dim3(8, 32), 256, 0, stream>>>(attnBf, WoutBf, bout, out,
                                                  4096, 1024, 1024, 0);
}

// Round 6
// 99.628 us; speedup vs baseline: 6.0323x; 1.2168x over previous
//
#include <hip/hip_runtime.h>
#include <cstddef>

#define B_  2
#define T_  2048
#define C_  1024
#define H_  16
#define D_  64
#define M_  64
#define NC_ 32
#define CH_ 64

typedef __attribute__((ext_vector_type(8))) short bf16x8;
typedef __attribute__((ext_vector_type(4))) float f32x4;

__device__ __forceinline__ ushort f2bf(float f) {
    union { float f; unsigned u; } v; v.f = f;
    unsigned r = v.u + 0x7FFF + ((v.u >> 16) & 1);   // RNE
    return (ushort)(r >> 16);
}
__device__ __forceinline__ float bf2f(ushort u) {
    union { unsigned u; float f; } x; x.u = ((unsigned)u) << 16; return x.f;
}

__device__ __forceinline__ void gld_lds16(const ushort* g, ushort* lds) {
    __builtin_amdgcn_global_load_lds(
        (const __attribute__((address_space(1))) unsigned int*)g,
        (__attribute__((address_space(3))) unsigned int*)lds,
        16, 0, 0);
}

// fragment read from a swizzled [R][64] bf16 LDS tile (128B rows, byte ^= (row&7)<<4)
__device__ __forceinline__ bf16x8 frag_ld(const ushort* lds, int row16, int k0, int lane) {
    int r = row16 + (lane & 15);
    int byte = ((k0 * 2) + ((lane >> 4) << 4)) ^ ((r & 7) << 4);
    return *(const bf16x8*)((const char*)lds + r * 128 + byte);
}

#define VMCNT(n) asm volatile("s_waitcnt vmcnt(" #n ")" ::: "memory")
#define BAR() do { __builtin_amdgcn_s_barrier(); __builtin_amdgcn_sched_barrier(0); } while (0)

// ================= fused prep: weight combine + casts + bias =================
// seg0 [0,256): q'/k' combine, block=(sel,h,cchunk of 128 cols), LDS-tiled
// seg1 [256,512): v-part copy+cast Wqkv[2048..3071][*] -> Wbt rows 2048..
// seg2 [512,1536): x fp32->bf16 cast
// seg3 [1536,1792): Wout fp32->bf16 cast
// seg4 [1792,1804): bbig
#define SEG1_ 256
#define SEG2_ 512
#define SEG3_ 1536
#define SEG4_ 1792
#define NPREP_ 1804

__global__ __launch_bounds__(256) void prep_all(
    const float* __restrict__ x, const float* __restrict__ Wqkv,
    const float* __restrict__ bqkv, const float* __restrict__ Wout,
    const float* __restrict__ proj,
    ushort* __restrict__ Wbt, ushort* __restrict__ xbf,
    ushort* __restrict__ WoutBf, float* __restrict__ bbig)
{
    __shared__ float Ws[64 * 128];
    __shared__ float Ps[64 * 64];
    const int blk = blockIdx.x, t = threadIdx.x;
    if (blk < SEG1_) {
        // ---- combine: Wbt[sel*1024 + h*64 + m][cc*128 + c] = sum_d Wqkv[(sel*1024+h*64+d)][c]*proj[h][d][m]
        const int sel = blk >> 7, h = (blk >> 3) & 15, cc = blk & 7;
        const int rowbase = sel * 1024 + h * 64;
        {
            const int r0 = t >> 5, cq = t & 31;
#pragma unroll
            for (int k = 0; k < 8; ++k) {
                int r = r0 + 8 * k;
                *(float4*)&Ws[r * 128 + cq * 4] =
                    *(const float4*)&Wqkv[(size_t)(rowbase + r) * 1024 + cc * 128 + cq * 4];
            }
        }
#pragma unroll
        for (int k = 0; k < 4; ++k) {
            int i4 = t + 256 * k;
            *(float4*)&Ps[i4 * 4] = *(const float4*)&proj[h * 4096 + i4 * 4];
        }
        __syncthreads();
#pragma unroll
        for (int k = 0; k < 2; ++k) {
            int id = t + 256 * k;
            int m4 = id >> 5, c4 = id & 31;
            float4 a0 = {0.f,0.f,0.f,0.f}, a1 = a0, a2 = a0, a3 = a0;
            for (int d = 0; d < 64; ++d) {
                float4 w = *(const float4*)&Ws[d * 128 + c4 * 4];
                float4 p = *(const float4*)&Ps[d * 64 + m4 * 4];
                a0.x += p.x*w.x; a0.y += p.x*w.y; a0.z += p.x*w.z; a0.w += p.x*w.w;
                a1.x += p.y*w.x; a1.y += p.y*w.y; a1.z += p.y*w.z; a1.w += p.y*w.w;
                a2.x += p.z*w.x; a2.y += p.z*w.y; a2.z += p.z*w.z; a2.w += p.z*w.w;
                a3.x += p.w*w.x; a3.y += p.w*w.y; a3.z += p.w*w.z; a3.w += p.w*w.w;
            }
            size_t obase = (size_t)(rowbase + m4 * 4) * 1024 + cc * 128 + c4 * 4;
            ushort4 o0 = { f2bf(a0.x), f2bf(a0.y), f2bf(a0.z), f2bf(a0.w) };
            ushort4 o1 = { f2bf(a1.x), f2bf(a1.y), f2bf(a1.z), f2bf(a1.w) };
            ushort4 o2 = { f2bf(a2.x), f2bf(a2.y), f2bf(a2.z), f2bf(a2.w) };
            ushort4 o3 = { f2bf(a3.x), f2bf(a3.y), f2bf(a3.z), f2bf(a3.w) };
            *(ushort4*)&Wbt[obase]          = o0;
            *(ushort4*)&Wbt[obase + 1024]   = o1;
            *(ushort4*)&Wbt[obase + 2048]   = o2;
            *(ushort4*)&Wbt[obase + 3072]   = o3;
        }
    } else if (blk < SEG2_) {
        // ---- v-part: Wbt[2048+r][c] = Wqkv[2048+r][c]
        int bo = blk - SEG1_;
#pragma unroll
        for (int pass = 0; pass < 4; ++pass) {
            int i4 = bo * 1024 + pass * 256 + t;
            float4 v = ((const float4*)Wqkv)[524288 + i4];
            ushort4 o = { f2bf(v.x), f2bf(v.y), f2bf(v.z), f2bf(v.w) };
            ((ushort4*)(Wbt + 2097152))[i4] = o;
        }
    } else if (blk < SEG3_) {
        int bo = blk - SEG2_;
#pragma unroll
        for (int pass = 0; pass < 4; ++pass) {
            int i4 = bo * 1024 + pass * 256 + t;
            float4 v = ((const float4*)x)[i4];
            ushort4 o = { f2bf(v.x), f2bf(v.y), f2bf(v.z), f2bf(v.w) };
            ((ushort4*)xbf)[i4] = o;
        }
    } else if (blk < SEG4_) {
        int bo = blk - SEG3_;
#pragma unroll
        for (int pass = 0; pass < 4; ++pass) {
            int i4 = bo * 1024 + pass * 256 + t;
            float4 v = ((const float4*)Wout)[i4];
            ushort4 o = { f2bf(v.x), f2bf(v.y), f2bf(v.z), f2bf(v.w) };
            ((ushort4*)WoutBf)[i4] = o;
        }
    } else {
        int j = (blk - SEG4_) * 256 + t;
        if (j < 2048) {
            int sel = j >> 10, hm = j & 1023, h = hm >> 6, m = hm & 63;
            const float* b = bqkv + sel * C_ + h * D_;
            const float* p = proj + (size_t)h * D_ * M_ + m;
            float acc = 0.f;
#pragma unroll 8
            for (int d = 0; d < D_; ++d) acc += b[d] * p[(size_t)d * M_];
            bbig[j] = acc;
        } else {
            bbig[j] = bqkv[j];
        }
    }
}

// ================= 8-phase pipelined GEMM1: C = relu?(A[M][K] @ Bt[N][K]^T + bias) =================
__device__ __forceinline__ void stage_G0(const ushort* __restrict__ Ag, const ushort* __restrict__ Bg,
                                         ushort* Abuf, ushort* Bbuf,
                                         int m0, int n0, int K, int kcol, int w, int lane) {
    const int l8 = lane >> 3, lc = (lane & 7) * 8;   // lc in ushort units
#pragma unroll
    for (int i = 0; i < 4; ++i) {
        int c = w * 4 + i;
        if (c < 8) {
            int fr = (c < 4) ? c * 8 : 64 + (c - 4) * 8;
            int r = fr + l8;
            int cs = lc ^ ((r & 7) << 3);
            gld_lds16(Ag + (size_t)(m0 + r) * K + kcol + cs, Abuf + fr * 64);
        } else {
            int cb = c - 8, g = cb / 6, k8 = cb - g * 6;
            int fr = g * 96 + k8 * 8;
            int r = fr + l8;
            int cs = lc ^ ((r & 7) << 3);
            gld_lds16(Bg + (size_t)(n0 + r) * K + kcol + cs, Bbuf + fr * 64);
        }
    }
}

__device__ __forceinline__ void stage_G1(const ushort* __restrict__ Ag, const ushort* __restrict__ Bg,
                                         ushort* Abuf, ushort* Bbuf,
                                         int m0, int n0, int K, int kcol, int w, int lane) {
    const int l8 = lane >> 3, lc = (lane & 7) * 8;
#pragma unroll
    for (int i = 0; i < 3; ++i) {                    // B first (needed at phase 1)
        int cb = w * 3 + i, g = cb / 6, k8 = cb - g * 6;
        int fr = g * 96 + 48 + k8 * 8;
        int r = fr + l8;
        int cs = lc ^ ((r & 7) << 3);
        gld_lds16(Bg + (size_t)(n0 + r) * K + kcol + cs, Bbuf + fr * 64);
    }
    {                                                // A half1 (needed at phase 2)
        int fr = (w < 4) ? 32 + w * 8 : 96 + (w - 4) * 8;
        int r = fr + l8;
        int cs = lc ^ ((r & 7) << 3);
        gld_lds16(Ag + (size_t)(m0 + r) * K + kcol + cs, Abuf + fr * 64);
    }
}

__device__ __forceinline__ void phase_mfma(const ushort* Abuf, const ushort* Bbuf,
                                           f32x4 (&acc)[4][6], int wr, int wc, int lane,
                                           int Mh, int Nh) {
    bf16x8 a[2][2], b[3][2];
#pragma unroll
    for (int i = 0; i < 2; ++i)
#pragma unroll
        for (int ks = 0; ks < 2; ++ks)
            a[i][ks] = frag_ld(Abuf, wr + Mh * 32 + i * 16, ks * 32, lane);
#pragma unroll
    for (int j = 0; j < 3; ++j)
#pragma unroll
        for (int ks = 0; ks < 2; ++ks)
            b[j][ks] = frag_ld(Bbuf, wc + Nh * 48 + j * 16, ks * 32, lane);
    __builtin_amdgcn_s_setprio(1);
#pragma unroll
    for (int ks = 0; ks < 2; ++ks)
#pragma unroll
        for (int i = 0; i < 2; ++i)
#pragma unroll
            for (int j = 0; j < 3; ++j)
                acc[Mh * 2 + i][Nh * 3 + j] = __builtin_amdgcn_mfma_f32_16x16x32_bf16(
                    a[i][ks], b[j][ks], acc[Mh * 2 + i][Nh * 3 + j], 0, 0, 0);
    __builtin_amdgcn_s_setprio(0);
}

__global__ __launch_bounds__(512) void gemm_8phase(
    const ushort* __restrict__ A,    // [M][K] bf16
    const ushort* __restrict__ Bt,   // [N][K] bf16
    const float* __restrict__ bias,
    ushort* __restrict__ Cout,       // [M][N] bf16
    int M, int N, int K, int reluLimit)
{
    __shared__ __align__(16) ushort lds[65536];      // 128 KiB

    const int tid = threadIdx.x, w = tid >> 6, lane = tid & 63;
    const int m0 = blockIdx.y * 128, n0 = blockIdx.x * 384;
    const int wr = (w >> 2) * 64, wc = (w & 3) * 96;
    f32x4 acc[4][6] = {};
    const int NT = K / 64;

    stage_G0(A, Bt, lds, lds + 16384, m0, n0, K, 0, w, lane);
    stage_G1(A, Bt, lds, lds + 16384, m0, n0, K, 0, w, lane);

    for (int kt = 0; kt < NT - 1; ++kt) {
        const int p = kt & 1;
        ushort* Acur = lds + p * 8192;
        ushort* Anxt = lds + (p ^ 1) * 8192;
        ushort* Bcur = lds + 16384 + p * 24576;
        ushort* Bnxt = lds + 16384 + (p ^ 1) * 24576;
        const int kc1 = (kt + 1) * 64;
        VMCNT(4); BAR();
        stage_G0(A, Bt, Anxt, Bnxt, m0, n0, K, kc1, w, lane);
        phase_mfma(Acur, Bcur, acc, wr, wc, lane, 0, 0);
        VMCNT(5); BAR();
        phase_mfma(Acur, Bcur, acc, wr, wc, lane, 0, 1);
        VMCNT(4); BAR();
        stage_G1(A, Bt, Anxt, Bnxt, m0, n0, K, kc1, w, lane);
        phase_mfma(Acur, Bcur, acc, wr, wc, lane, 1, 0);
        phase_mfma(Acur, Bcur, acc, wr, wc, lane, 1, 1);
    }
    {
        const int p = (NT - 1) & 1;
        ushort* Acur = lds + p * 8192;
        ushort* Bcur = lds + 16384 + p * 24576;
        VMCNT(4); BAR();
        phase_mfma(Acur, Bcur, acc, wr, wc, lane, 0, 0);
        VMCNT(1); BAR();
        phase_mfma(Acur, Bcur, acc, wr, wc, lane, 0, 1);
        VMCNT(0); BAR();
        phase_mfma(Acur, Bcur, acc, wr, wc, lane, 1, 0);
        phase_mfma(Acur, Bcur, acc, wr, wc, lane, 1, 1);
    }

    const int crow = (lane >> 4) * 4, ccol = lane & 15;
#pragma unroll
    for (int nj = 0; nj < 6; ++nj) {
        int col = n0 + wc + nj * 16 + ccol;
        float bv = bias[col];
        bool rl = col < reluLimit;
#pragma unroll
        for (int mi = 0; mi < 4; ++mi) {
#pragma unroll
            for (int rr = 0; rr < 4; ++rr) {
                int row = m0 + wr + mi * 16 + crow + rr;
                float v = acc[mi][nj][rr] + bv;
                if (rl) v = fmaxf(v, 0.f);
                Cout[(size_t)row * N + col] = f2bf(v);
            }
        }
    }
}

// ---------------- m97-structure MFMA GEMM (fp32 out) for GEMM2 ----------------
__global__ __launch_bounds__(256, 2) void gemm_mfma_bt(
    const ushort* __restrict__ A, const ushort* __restrict__ Bt,
    const float* __restrict__ bias, float* __restrict__ Cmat,
    int M, int N, int K, int reluLimit)
{
    __shared__ __align__(16) ushort As[128 * 32];
    __shared__ __align__(16) ushort Bs[128 * 32];
    const int tid  = threadIdx.x;
    const int wave = tid >> 6, lane = tid & 63;
    const int m0 = blockIdx.y * 128, n0 = blockIdx.x * 128;
    const int wr = (wave >> 1) * 64, wc = (wave & 1) * 64;
    f32x4 acc[4][4] = {};

    const int lrow = lane >> 2;
    const int lcol = (lane & 3) * 8;
    ushort* AsB0 = &As[(wave * 2 + 0) * 512];
    ushort* AsB1 = &As[(wave * 2 + 1) * 512];
    ushort* BsB0 = &Bs[(wave * 2 + 0) * 512];
    ushort* BsB1 = &Bs[(wave * 2 + 1) * 512];
    const ushort* Ag0 = A  + (size_t)(m0 + wave * 32 + lrow) * K + lcol;
    const ushort* Ag1 = Ag0 + (size_t)16 * K;
    const ushort* Bg0 = Bt + (size_t)(n0 + wave * 32 + lrow) * K + lcol;
    const ushort* Bg1 = Bg0 + (size_t)16 * K;

    const int frow = lane & 15, fk = (lane >> 4) * 8;

    for (int k0 = 0; k0 < K; k0 += 32) {
        __syncthreads();
        gld_lds16(Ag0 + k0, AsB0);
        gld_lds16(Ag1 + k0, AsB1);
        gld_lds16(Bg0 + k0, BsB0);
        gld_lds16(Bg1 + k0, BsB1);
        __syncthreads();
        bf16x8 af[4], bfr[4];
#pragma unroll
        for (int i = 0; i < 4; ++i)
            af[i] = *(const bf16x8*)&As[(wr + i * 16 + frow) * 32 + fk];
#pragma unroll
        for (int j = 0; j < 4; ++j)
            bfr[j] = *(const bf16x8*)&Bs[(wc + j * 16 + frow) * 32 + fk];
#pragma unroll
        for (int i = 0; i < 4; ++i)
#pragma unroll
            for (int j = 0; j < 4; ++j)
                acc[i][j] = __builtin_amdgcn_mfma_f32_16x16x32_bf16(af[i], bfr[j], acc[i][j], 0, 0, 0);
    }

    const int crow = (lane >> 4) * 4, ccol = lane & 15;
#pragma unroll
    for (int j = 0; j < 4; ++j) {
        int col = n0 + wc + j * 16 + ccol;
        float bv = bias[col];
        bool rl = col < reluLimit;
#pragma unroll
        for (int i = 0; i < 4; ++i) {
#pragma unroll
            for (int r = 0; r < 4; ++r) {
                int row = m0 + wr + i * 16 + crow + r;
                float v = acc[i][j][r] + bv;
                if (rl) v = fmaxf(v, 0.f);
                Cmat[(size_t)row * N + col] = v;
            }
        }
    }
}

// ---------------- chunk_kv: transpose K,V per chunk; St = Vt@Kt^T; sK sums ----------------
__global__ __launch_bounds__(256) void chunk_kv_mfma(
    const ushort* __restrict__ out1, ushort* __restrict__ VtG,
    float* __restrict__ St, float* __restrict__ sks)
{
    __shared__ unsigned Tl[64 * 76];
    __shared__ ushort Ktb[64 * 64];
    __shared__ ushort Vtb[64 * 64];
    __shared__ float skp[4][64];
    const int blk = blockIdx.x, c = blk & 31, bh = blk >> 5;
    const int b = bh >> 4, h = bh & 15, t0 = c * CH_;
    const int tid = threadIdx.x, wave = tid >> 6, lane = tid & 63;
    const ushort* kg = out1 + (size_t)(b * T_ + t0) * 3072 + C_ + h * D_;
    const ushort* vg = kg + C_;

#pragma unroll
    for (int it = 0; it < 2; ++it) {
        int i = tid + it * 256, r = i >> 3, sl = i & 7;
        bf16x8 v = *(const bf16x8*)(kg + (size_t)r * 3072 + sl * 8);
        unsigned* dst = &Tl[r * 76 + sl * 8];
        uint4 w0 = { (ushort)v[0], (ushort)v[1], (ushort)v[2], (ushort)v[3] };
        uint4 w1 = { (ushort)v[4], (ushort)v[5], (ushort)v[6], (ushort)v[7] };
        *(uint4*)dst = w0;
        *(uint4*)(dst + 4) = w1;
    }
    __syncthreads();
    {
        int m = tid >> 2, tc = tid & 3;
        bf16x8 va, vb;
        float s = 0.f;
#pragma unroll
        for (int k = 0; k < 8; ++k) {
            ushort u = (ushort)Tl[(tc * 16 + k) * 76 + m];
            va[k] = (short)u; s += bf2f(u);
        }
#pragma unroll
        for (int k = 0; k < 8; ++k) {
            ushort u = (ushort)Tl[(tc * 16 + 8 + k) * 76 + m];
            vb[k] = (short)u; s += bf2f(u);
        }
        skp[tc][m] = s;
        int b0 = (tc * 32) ^ ((m & 7) << 4);
        int b1 = (tc * 32 + 16) ^ ((m & 7) << 4);
        *(bf16x8*)((char*)Ktb + m * 128 + b0) = va;
        *(bf16x8*)((char*)Ktb + m * 128 + b1) = vb;
    }
    __syncthreads();
#pragma unroll
    for (int it = 0; it < 2; ++it) {
        int i = tid + it * 256, r = i >> 3, sl = i & 7;
        bf16x8 v = *(const bf16x8*)(vg + (size_t)r * 3072 + sl * 8);
        unsigned* dst = &Tl[r * 76 + sl * 8];
        uint4 w0 = { (ushort)v[0], (ushort)v[1], (ushort)v[2], (ushort)v[3] };
        uint4 w1 = { (ushort)v[4], (ushort)v[5], (ushort)v[6], (ushort)v[7] };
        *(uint4*)dst = w0;
        *(uint4*)(dst + 4) = w1;
    }
    __syncthreads();
    {
        int d = tid >> 2, tc = tid & 3;
        bf16x8 va, vb;
#pragma unroll
        for (int k = 0; k < 8; ++k) va[k] = (short)(ushort)Tl[(tc * 16 + k) * 76 + d];
#pragma unroll
        for (int k = 0; k < 8; ++k) vb[k] = (short)(ushort)Tl[(tc * 16 + 8 + k) * 76 + d];
        int b0 = (tc * 32) ^ ((d & 7) << 4);
        int b1 = (tc * 32 + 16) ^ ((d & 7) << 4);
        *(bf16x8*)((char*)Vtb + d * 128 + b0) = va;
        *(bf16x8*)((char*)Vtb + d * 128 + b1) = vb;
        ushort* og = VtG + (size_t)blk * 4096 + d * 64 + tc * 16;
        *(bf16x8*)og = va;
        *(bf16x8*)(og + 8) = vb;
    }
    __syncthreads();
    const int wr = wave * 16, g = lane >> 4, ccol = lane & 15;
    f32x4 acc[4] = {};
#pragma unroll
    for (int k0 = 0; k0 < 64; k0 += 32) {
        bf16x8 av = frag_ld(Vtb, wr, k0, lane);
#pragma unroll
        for (int j = 0; j < 4; ++j)
            acc[j] = __builtin_amdgcn_mfma_f32_16x16x32_bf16(av, frag_ld(Ktb, j * 16, k0, lane), acc[j], 0, 0, 0);
    }
    float* stg = St + (size_t)blk * 4096;
#pragma unroll
    for (int j = 0; j < 4; ++j)
#pragma unroll
        for (int r = 0; r < 4; ++r)
            stg[(wr + g * 4 + r) * 64 + j * 16 + ccol] = acc[j][r];
    if (tid < 64)
        sks[(size_t)blk * 64 + tid] = skp[0][tid] + skp[1][tid] + skp[2][tid] + skp[3][tid];
}

// ---------------- parallel exclusive chunk-prefix scan ----------------
__global__ __launch_bounds__(256) void chunk_scan2(const float* __restrict__ St,
                                                   const float* __restrict__ sks,
                                                   ushort* __restrict__ Sbf,
                                                   ushort* __restrict__ skb) {
    if (blockIdx.x < 512) {
        int id = blockIdx.x * 256 + threadIdx.x;
        int bh = id >> 12, e = id & 4095;
        const float* p = St + (size_t)bh * NC_ * 4096 + e;
        ushort* q = Sbf + (size_t)bh * NC_ * 4096 + e;
        float run = 0.f;
        for (int c = 0; c < NC_; ++c) {
            q[(size_t)c * 4096] = f2bf(run);
            run += p[(size_t)c * 4096];
        }
    } else {
        int id2 = (blockIdx.x - 512) * 256 + threadIdx.x;
        int bh = id2 >> 6, m = id2 & 63;
        const float* p = sks + (size_t)bh * NC_ * 64 + m;
        ushort* q = skb + (size_t)bh * NC_ * 64 + m;
        float run = 0.f;
        for (int c = 0; c < NC_; ++c) {
            q[c * 64] = f2bf(run);
            run += p[c * 64];
        }
    }
}

// ---------------- chunk attention (all-MFMA) ----------------
__global__ __launch_bounds__(256) void chunk_attn_mfma(
    const ushort* __restrict__ out1, const ushort* __restrict__ VtG,
    const ushort* __restrict__ Sbf, const ushort* __restrict__ skb,
    ushort* __restrict__ attnBf)
{
    __shared__ ushort Ql[64 * 64];
    __shared__ ushort Kl[64 * 64];
    __shared__ ushort Vl[64 * 64];
    __shared__ ushort Al[64 * 64];
    __shared__ ushort Sl[80 * 64];
    const int blk = blockIdx.x, c = blk & 31, bh = blk >> 5;
    const int b = bh >> 4, h = bh & 15, t0 = c * CH_;
    const int tid = threadIdx.x, wave = tid >> 6, lane = tid & 63;
    const ushort* qg  = out1 + (size_t)(b * T_ + t0) * 3072 + h * D_;
    const ushort* kg  = qg + C_;
    const ushort* vtg = VtG + (size_t)blk * 4096;
    const ushort* sbg = Sbf + (size_t)blk * 4096;
#pragma unroll
    for (int it = 0; it < 2; ++it) {
        int i = tid + it * 256, r = i >> 3, sl = i & 7;
        int lo = (sl * 16) ^ ((r & 7) << 4);
        *(bf16x8*)((char*)Ql + r * 128 + lo) = *(const bf16x8*)(qg + (size_t)r * 3072 + sl * 8);
        *(bf16x8*)((char*)Kl + r * 128 + lo) = *(const bf16x8*)(kg + (size_t)r * 3072 + sl * 8);
        *(bf16x8*)((char*)Vl + r * 128 + lo) = *(const bf16x8*)(vtg + r * 64 + sl * 8);
        *(bf16x8*)((char*)Sl + r * 128 + lo) = *(const bf16x8*)(sbg + r * 64 + sl * 8);
    }
    if (tid < 8)
        *(bf16x8*)((char*)Sl + 64 * 128 + tid * 16) = *(const bf16x8*)(skb + (size_t)blk * 64 + tid * 8);
    __syncthreads();

    const int wr = wave * 16, g = lane >> 4, ccol = lane & 15;
    f32x4 accA[4] = {};
#pragma unroll
    for (int k0 = 0; k0 < 64; k0 += 32) {
        bf16x8 aq = frag_ld(Ql, wr, k0, lane);
#pragma unroll
        for (int j = 0; j < 4; ++j)
            accA[j] = __builtin_amdgcn_mfma_f32_16x16x32_bf16(aq, frag_ld(Kl, j * 16, k0, lane), accA[j], 0, 0, 0);
    }
    float rsum[4] = {0.f, 0.f, 0.f, 0.f};
#pragma unroll
    for (int j = 0; j < 4; ++j) {
#pragma unroll
        for (int r = 0; r < 4; ++r) {
            int tl = wr + g * 4 + r, sl2 = j * 16 + ccol;
            float v = (sl2 <= tl) ? accA[j][r] : 0.f;
            rsum[r] += v;
            *(ushort*)((char*)Al + tl * 128 + ((sl2 * 2) ^ ((tl & 7) << 4))) = f2bf(v);
        }
    }
#pragma unroll
    for (int r = 0; r < 4; ++r) {
        rsum[r] += __shfl_xor(rsum[r], 1);
        rsum[r] += __shfl_xor(rsum[r], 2);
        rsum[r] += __shfl_xor(rsum[r], 4);
        rsum[r] += __shfl_xor(rsum[r], 8);
    }
    f32x4 accC[4] = {};
    f32x4 accE = {};
#pragma unroll
    for (int k0 = 0; k0 < 64; k0 += 32) {
        bf16x8 aa = frag_ld(Al, wr, k0, lane);
#pragma unroll
        for (int j = 0; j < 4; ++j)
            accC[j] = __builtin_amdgcn_mfma_f32_16x16x32_bf16(aa, frag_ld(Vl, j * 16, k0, lane), accC[j], 0, 0, 0);
    }
#pragma unroll
    for (int k0 = 0; k0 < 64; k0 += 32) {
        bf16x8 aq = frag_ld(Ql, wr, k0, lane);
#pragma unroll
        for (int j = 0; j < 4; ++j)
            accC[j] = __builtin_amdgcn_mfma_f32_16x16x32_bf16(aq, frag_ld(Sl, j * 16, k0, lane), accC[j], 0, 0, 0);
        accE = __builtin_amdgcn_mfma_f32_16x16x32_bf16(aq, frag_ld(Sl, 64, k0, lane), accE, 0, 0, 0);
    }
    ushort* og = attnBf + (size_t)(b * T_ + t0) * C_ + h * D_;
#pragma unroll
    for (int r = 0; r < 4; ++r) {
        float nq = __shfl(accE[r], (lane & 48));
        float inv = 1.f / (nq + rsum[r] + 1e-6f);
        int tl = wr + g * 4 + r;
#pragma unroll
        for (int j = 0; j < 4; ++j)
            og[(size_t)tl * C_ + j * 16 + ccol] = f2bf(accC[j][r] * inv);
    }
}

extern "C" void kernel_launch(void* const* d_in, const int* in_sizes, int n_in,
                              void* d_out, int out_size, void* d_ws, size_t ws_size,
                              hipStream_t stream) {
    (void)in_sizes; (void)n_in; (void)out_size; (void)ws_size;
    const float* x    = (const float*)d_in[0];
    const float* Wqkv = (const float*)d_in[1];
    const float* bqkv = (const float*)d_in[2];
    const float* Wout = (const float*)d_in[3];
    const float* bout = (const float*)d_in[4];
    const float* proj = (const float*)d_in[5];
    float* out = (float*)d_out;
    char* ws = (char*)d_ws;

    ushort* Wbt    = (ushort*)(ws);                 // 6 MB
    ushort* xbf    = (ushort*)(ws + (6ull  << 20)); // 8 MB
    ushort* WoutBf = (ushort*)(ws + (14ull << 20)); // 2 MB
    ushort* attnBf = (ushort*)(ws + (16ull << 20)); // 8 MB
    float*  bbig   = (float*) (ws + (24ull << 20)); // 12 KB
    ushort* out1   = (ushort*)(ws + (25ull << 20)); // 24 MB (bf16 q'|k'|v)
    ushort* VtG    = (ushort*)(ws + (49ull << 20)); // 8 MB
    float*  St     = (float*) (ws + (57ull << 20)); // 16 MB
    ushort* Sbf    = (ushort*)(ws + (73ull << 20)); // 8 MB
    float*  sks    = (float*) (ws + (81ull << 20)); // 256 KB
    ushort* skb    = (ushort*)(ws + (82ull << 20)); // 128 KB

    prep_all<<<NPREP_, 256, 0, stream>>>(x, Wqkv, bqkv, Wout, proj,
                                         Wbt, xbf, WoutBf, bbig);
    gemm_8phase<<<dim3(8, 32), 512, 0, stream>>>(xbf, Wbt, bbig, out1,
                                                 4096, 3072, 1024, 2048);
    chunk_kv_mfma<<<1024, 256, 0, stream>>>(out1, VtG, St, sks);
    chunk_scan2<<<520, 256, 0, stream>>>(St, sks, Sbf, skb);
    chunk_attn_mfma<<<1024, 256, 0, stream>>>(out1, VtG, Sbf, skb, attnBf);
    gemm_mfma_bt<<<dim3(8, 32), 256, 0, stream>>>(attnBf, WoutBf, bout, out,
                                                  4096, 1024, 1024, 0);
}

// Round 8
// 88.792 us; speedup vs baseline: 6.7684x; 1.1220x over previous
//
#include <hip/hip_runtime.h>
#include <cstddef>

#define B_  2
#define T_  2048
#define C_  1024
#define H_  16
#define D_  64
#define M_  64
#define NC_ 32
#define CH_ 64

typedef __attribute__((ext_vector_type(8))) short bf16x8;
typedef __attribute__((ext_vector_type(4))) float f32x4;

__device__ __forceinline__ ushort f2bf(float f) {
    union { float f; unsigned u; } v; v.f = f;
    unsigned r = v.u + 0x7FFF + ((v.u >> 16) & 1);   // RNE
    return (ushort)(r >> 16);
}
__device__ __forceinline__ float bf2f(ushort u) {
    union { unsigned u; float f; } x; x.u = ((unsigned)u) << 16; return x.f;
}

__device__ __forceinline__ void gld_lds16(const ushort* g, ushort* lds) {
    __builtin_amdgcn_global_load_lds(
        (const __attribute__((address_space(1))) unsigned int*)g,
        (__attribute__((address_space(3))) unsigned int*)lds,
        16, 0, 0);
}

// fragment read from a swizzled [R][64] bf16 LDS tile (128B rows, byte ^= (row&7)<<4)
__device__ __forceinline__ bf16x8 frag_ld(const ushort* lds, int row16, int k0, int lane) {
    int r = row16 + (lane & 15);
    int byte = ((k0 * 2) + ((lane >> 4) << 4)) ^ ((r & 7) << 4);
    return *(const bf16x8*)((const char*)lds + r * 128 + byte);
}

#define VMCNT(n) asm volatile("s_waitcnt vmcnt(" #n ")" ::: "memory")
#define BAR() do { __builtin_amdgcn_s_barrier(); __builtin_amdgcn_sched_barrier(0); } while (0)

// ================= fused prep: weight combine + casts + bias =================
#define SEG1_ 256
#define SEG2_ 512
#define SEG3_ 1536
#define SEG4_ 1792
#define NPREP_ 1804

__global__ __launch_bounds__(256) void prep_all(
    const float* __restrict__ x, const float* __restrict__ Wqkv,
    const float* __restrict__ bqkv, const float* __restrict__ Wout,
    const float* __restrict__ proj,
    ushort* __restrict__ Wbt, ushort* __restrict__ xbf,
    ushort* __restrict__ WoutBf, float* __restrict__ bbig)
{
    __shared__ float Ws[64 * 128];
    __shared__ float Ps[64 * 64];
    const int blk = blockIdx.x, t = threadIdx.x;
    if (blk < SEG1_) {
        const int sel = blk >> 7, h = (blk >> 3) & 15, cc = blk & 7;
        const int rowbase = sel * 1024 + h * 64;
        {
            const int r0 = t >> 5, cq = t & 31;
#pragma unroll
            for (int k = 0; k < 8; ++k) {
                int r = r0 + 8 * k;
                *(float4*)&Ws[r * 128 + cq * 4] =
                    *(const float4*)&Wqkv[(size_t)(rowbase + r) * 1024 + cc * 128 + cq * 4];
            }
        }
#pragma unroll
        for (int k = 0; k < 4; ++k) {
            int i4 = t + 256 * k;
            *(float4*)&Ps[i4 * 4] = *(const float4*)&proj[h * 4096 + i4 * 4];
        }
        __syncthreads();
#pragma unroll
        for (int k = 0; k < 2; ++k) {
            int id = t + 256 * k;
            int m4 = id >> 5, c4 = id & 31;
            float4 a0 = {0.f,0.f,0.f,0.f}, a1 = a0, a2 = a0, a3 = a0;
            for (int d = 0; d < 64; ++d) {
                float4 w = *(const float4*)&Ws[d * 128 + c4 * 4];
                float4 p = *(const float4*)&Ps[d * 64 + m4 * 4];
                a0.x += p.x*w.x; a0.y += p.x*w.y; a0.z += p.x*w.z; a0.w += p.x*w.w;
                a1.x += p.y*w.x; a1.y += p.y*w.y; a1.z += p.y*w.z; a1.w += p.y*w.w;
                a2.x += p.z*w.x; a2.y += p.z*w.y; a2.z += p.z*w.z; a2.w += p.z*w.w;
                a3.x += p.w*w.x; a3.y += p.w*w.y; a3.z += p.w*w.z; a3.w += p.w*w.w;
            }
            size_t obase = (size_t)(rowbase + m4 * 4) * 1024 + cc * 128 + c4 * 4;
            ushort4 o0 = { f2bf(a0.x), f2bf(a0.y), f2bf(a0.z), f2bf(a0.w) };
            ushort4 o1 = { f2bf(a1.x), f2bf(a1.y), f2bf(a1.z), f2bf(a1.w) };
            ushort4 o2 = { f2bf(a2.x), f2bf(a2.y), f2bf(a2.z), f2bf(a2.w) };
            ushort4 o3 = { f2bf(a3.x), f2bf(a3.y), f2bf(a3.z), f2bf(a3.w) };
            *(ushort4*)&Wbt[obase]          = o0;
            *(ushort4*)&Wbt[obase + 1024]   = o1;
            *(ushort4*)&Wbt[obase + 2048]   = o2;
            *(ushort4*)&Wbt[obase + 3072]   = o3;
        }
    } else if (blk < SEG2_) {
        int bo = blk - SEG1_;
#pragma unroll
        for (int pass = 0; pass < 4; ++pass) {
            int i4 = bo * 1024 + pass * 256 + t;
            float4 v = ((const float4*)Wqkv)[524288 + i4];
            ushort4 o = { f2bf(v.x), f2bf(v.y), f2bf(v.z), f2bf(v.w) };
            ((ushort4*)(Wbt + 2097152))[i4] = o;
        }
    } else if (blk < SEG3_) {
        int bo = blk - SEG2_;
#pragma unroll
        for (int pass = 0; pass < 4; ++pass) {
            int i4 = bo * 1024 + pass * 256 + t;
            float4 v = ((const float4*)x)[i4];
            ushort4 o = { f2bf(v.x), f2bf(v.y), f2bf(v.z), f2bf(v.w) };
            ((ushort4*)xbf)[i4] = o;
        }
    } else if (blk < SEG4_) {
        int bo = blk - SEG3_;
#pragma unroll
        for (int pass = 0; pass < 4; ++pass) {
            int i4 = bo * 1024 + pass * 256 + t;
            float4 v = ((const float4*)Wout)[i4];
            ushort4 o = { f2bf(v.x), f2bf(v.y), f2bf(v.z), f2bf(v.w) };
            ((ushort4*)WoutBf)[i4] = o;
        }
    } else {
        int j = (blk - SEG4_) * 256 + t;
        if (j < 2048) {
            int sel = j >> 10, hm = j & 1023, h = hm >> 6, m = hm & 63;
            const float* b = bqkv + sel * C_ + h * D_;
            const float* p = proj + (size_t)h * D_ * M_ + m;
            float acc = 0.f;
#pragma unroll 8
            for (int d = 0; d < D_; ++d) acc += b[d] * p[(size_t)d * M_];
            bbig[j] = acc;
        } else {
            bbig[j] = bqkv[j];
        }
    }
}

// ================= 8-phase pipelined GEMM1 (BM=128, BN=384, BK=64) =================
__device__ __forceinline__ void stage_G0(const ushort* __restrict__ Ag, const ushort* __restrict__ Bg,
                                         ushort* Abuf, ushort* Bbuf,
                                         int m0, int n0, int K, int kcol, int w, int lane) {
    const int l8 = lane >> 3, lc = (lane & 7) * 8;
#pragma unroll
    for (int i = 0; i < 4; ++i) {
        int c = w * 4 + i;
        if (c < 8) {
            int fr = (c < 4) ? c * 8 : 64 + (c - 4) * 8;
            int r = fr + l8;
            int cs = lc ^ ((r & 7) << 3);
            gld_lds16(Ag + (size_t)(m0 + r) * K + kcol + cs, Abuf + fr * 64);
        } else {
            int cb = c - 8, g = cb / 6, k8 = cb - g * 6;
            int fr = g * 96 + k8 * 8;
            int r = fr + l8;
            int cs = lc ^ ((r & 7) << 3);
            gld_lds16(Bg + (size_t)(n0 + r) * K + kcol + cs, Bbuf + fr * 64);
        }
    }
}

__device__ __forceinline__ void stage_G1(const ushort* __restrict__ Ag, const ushort* __restrict__ Bg,
                                         ushort* Abuf, ushort* Bbuf,
                                         int m0, int n0, int K, int kcol, int w, int lane) {
    const int l8 = lane >> 3, lc = (lane & 7) * 8;
#pragma unroll
    for (int i = 0; i < 3; ++i) {
        int cb = w * 3 + i, g = cb / 6, k8 = cb - g * 6;
        int fr = g * 96 + 48 + k8 * 8;
        int r = fr + l8;
        int cs = lc ^ ((r & 7) << 3);
        gld_lds16(Bg + (size_t)(n0 + r) * K + kcol + cs, Bbuf + fr * 64);
    }
    {
        int fr = (w < 4) ? 32 + w * 8 : 96 + (w - 4) * 8;
        int r = fr + l8;
        int cs = lc ^ ((r & 7) << 3);
        gld_lds16(Ag + (size_t)(m0 + r) * K + kcol + cs, Abuf + fr * 64);
    }
}

__device__ __forceinline__ void phase_mfma(const ushort* Abuf, const ushort* Bbuf,
                                           f32x4 (&acc)[4][6], int wr, int wc, int lane,
                                           int Mh, int Nh) {
    bf16x8 a[2][2], b[3][2];
#pragma unroll
    for (int i = 0; i < 2; ++i)
#pragma unroll
        for (int ks = 0; ks < 2; ++ks)
            a[i][ks] = frag_ld(Abuf, wr + Mh * 32 + i * 16, ks * 32, lane);
#pragma unroll
    for (int j = 0; j < 3; ++j)
#pragma unroll
        for (int ks = 0; ks < 2; ++ks)
            b[j][ks] = frag_ld(Bbuf, wc + Nh * 48 + j * 16, ks * 32, lane);
    __builtin_amdgcn_s_setprio(1);
#pragma unroll
    for (int ks = 0; ks < 2; ++ks)
#pragma unroll
        for (int i = 0; i < 2; ++i)
#pragma unroll
            for (int j = 0; j < 3; ++j)
                acc[Mh * 2 + i][Nh * 3 + j] = __builtin_amdgcn_mfma_f32_16x16x32_bf16(
                    a[i][ks], b[j][ks], acc[Mh * 2 + i][Nh * 3 + j], 0, 0, 0);
    __builtin_amdgcn_s_setprio(0);
}

__global__ __launch_bounds__(512) void gemm_8phase(
    const ushort* __restrict__ A, const ushort* __restrict__ Bt,
    const float* __restrict__ bias, ushort* __restrict__ Cout,
    int M, int N, int K, int reluLimit)
{
    __shared__ __align__(16) ushort lds[65536];

    const int tid = threadIdx.x, w = tid >> 6, lane = tid & 63;
    const int m0 = blockIdx.y * 128, n0 = blockIdx.x * 384;
    const int wr = (w >> 2) * 64, wc = (w & 3) * 96;
    f32x4 acc[4][6] = {};
    const int NT = K / 64;

    stage_G0(A, Bt, lds, lds + 16384, m0, n0, K, 0, w, lane);
    stage_G1(A, Bt, lds, lds + 16384, m0, n0, K, 0, w, lane);

    for (int kt = 0; kt < NT - 1; ++kt) {
        const int p = kt & 1;
        ushort* Acur = lds + p * 8192;
        ushort* Anxt = lds + (p ^ 1) * 8192;
        ushort* Bcur = lds + 16384 + p * 24576;
        ushort* Bnxt = lds + 16384 + (p ^ 1) * 24576;
        const int kc1 = (kt + 1) * 64;
        VMCNT(4); BAR();
        stage_G0(A, Bt, Anxt, Bnxt, m0, n0, K, kc1, w, lane);
        phase_mfma(Acur, Bcur, acc, wr, wc, lane, 0, 0);
        VMCNT(5); BAR();
        phase_mfma(Acur, Bcur, acc, wr, wc, lane, 0, 1);
        VMCNT(4); BAR();
        stage_G1(A, Bt, Anxt, Bnxt, m0, n0, K, kc1, w, lane);
        phase_mfma(Acur, Bcur, acc, wr, wc, lane, 1, 0);
        phase_mfma(Acur, Bcur, acc, wr, wc, lane, 1, 1);
    }
    {
        const int p = (NT - 1) & 1;
        ushort* Acur = lds + p * 8192;
        ushort* Bcur = lds + 16384 + p * 24576;
        VMCNT(4); BAR();
        phase_mfma(Acur, Bcur, acc, wr, wc, lane, 0, 0);
        VMCNT(1); BAR();
        phase_mfma(Acur, Bcur, acc, wr, wc, lane, 0, 1);
        VMCNT(0); BAR();
        phase_mfma(Acur, Bcur, acc, wr, wc, lane, 1, 0);
        phase_mfma(Acur, Bcur, acc, wr, wc, lane, 1, 1);
    }

    const int crow = (lane >> 4) * 4, ccol = lane & 15;
#pragma unroll
    for (int nj = 0; nj < 6; ++nj) {
        int col = n0 + wc + nj * 16 + ccol;
        float bv = bias[col];
        bool rl = col < reluLimit;
#pragma unroll
        for (int mi = 0; mi < 4; ++mi) {
#pragma unroll
            for (int rr = 0; rr < 4; ++rr) {
                int row = m0 + wr + mi * 16 + crow + rr;
                float v = acc[mi][nj][rr] + bv;
                if (rl) v = fmaxf(v, 0.f);
                Cout[(size_t)row * N + col] = f2bf(v);
            }
        }
    }
}

// ================= 8-phase GEMM2 (BM=128, BN=128, BK=64, 2 blocks/CU) =================
__device__ __forceinline__ void g2_stage_G0(const ushort* __restrict__ Ag, const ushort* __restrict__ Bg,
                                            ushort* Abuf, ushort* Bbuf,
                                            int m0, int n0, int K, int kcol, int w, int lane) {
    const int l8 = lane >> 3, lc = (lane & 7) * 8;
    {
        int rbase = (w < 4) ? w * 8 : 64 + (w - 4) * 8;
        int r = rbase + l8;
        int cs = lc ^ ((r & 7) << 3);
        gld_lds16(Ag + (size_t)(m0 + r) * K + kcol + cs, Abuf + rbase * 64);
    }
    {
        int rbase = (w >> 1) * 32 + (w & 1) * 8;
        int r = rbase + l8;
        int cs = lc ^ ((r & 7) << 3);
        gld_lds16(Bg + (size_t)(n0 + r) * K + kcol + cs, Bbuf + rbase * 64);
    }
}

__device__ __forceinline__ void g2_stage_G1(const ushort* __restrict__ Ag, const ushort* __restrict__ Bg,
                                            ushort* Abuf, ushort* Bbuf,
                                            int m0, int n0, int K, int kcol, int w, int lane) {
    const int l8 = lane >> 3, lc = (lane & 7) * 8;
    {   // B first (needed at phase 1): rows {16-31,48-63,80-95,112-127}
        int rbase = 16 + (w >> 1) * 32 + (w & 1) * 8;
        int r = rbase + l8;
        int cs = lc ^ ((r & 7) << 3);
        gld_lds16(Bg + (size_t)(n0 + r) * K + kcol + cs, Bbuf + rbase * 64);
    }
    {   // A Mh1 half: rows {32-63, 96-127}  (FIXED: was 64-95 for w>=4)
        int rbase = (w < 4) ? 32 + w * 8 : 96 + (w - 4) * 8;
        int r = rbase + l8;
        int cs = lc ^ ((r & 7) << 3);
        gld_lds16(Ag + (size_t)(m0 + r) * K + kcol + cs, Abuf + rbase * 64);
    }
}

__device__ __forceinline__ void g2_phase(const ushort* Abuf, const ushort* Bbuf,
                                         f32x4 (&acc)[4][2], int wr, int wc, int lane,
                                         int Mh, int Nh) {
    bf16x8 a[2][2], b[2];
#pragma unroll
    for (int i = 0; i < 2; ++i)
#pragma unroll
        for (int ks = 0; ks < 2; ++ks)
            a[i][ks] = frag_ld(Abuf, wr + Mh * 32 + i * 16, ks * 32, lane);
#pragma unroll
    for (int ks = 0; ks < 2; ++ks)
        b[ks] = frag_ld(Bbuf, wc + Nh * 16, ks * 32, lane);
    __builtin_amdgcn_s_setprio(1);
#pragma unroll
    for (int ks = 0; ks < 2; ++ks)
#pragma unroll
        for (int i = 0; i < 2; ++i)
            acc[Mh * 2 + i][Nh] = __builtin_amdgcn_mfma_f32_16x16x32_bf16(
                a[i][ks], b[ks], acc[Mh * 2 + i][Nh], 0, 0, 0);
    __builtin_amdgcn_s_setprio(0);
}

__global__ __launch_bounds__(512, 4) void gemm2_8phase(
    const ushort* __restrict__ A, const ushort* __restrict__ Bt,
    const float* __restrict__ bias, float* __restrict__ Cout,
    int M, int N, int K)
{
    __shared__ __align__(16) ushort lds[32768];      // 64 KiB

    const int tid = threadIdx.x, w = tid >> 6, lane = tid & 63;
    const int m0 = blockIdx.y * 128, n0 = blockIdx.x * 128;
    const int wr = (w >> 2) * 64, wc = (w & 3) * 32;
    f32x4 acc[4][2] = {};
    const int NT = K / 64;

    g2_stage_G0(A, Bt, lds, lds + 16384, m0, n0, K, 0, w, lane);
    g2_stage_G1(A, Bt, lds, lds + 16384, m0, n0, K, 0, w, lane);

    for (int kt = 0; kt < NT - 1; ++kt) {
        const int p = kt & 1;
        ushort* Acur = lds + p * 8192;
        ushort* Anxt = lds + (p ^ 1) * 8192;
        ushort* Bcur = lds + 16384 + p * 8192;
        ushort* Bnxt = lds + 16384 + (p ^ 1) * 8192;
        const int kc1 = (kt + 1) * 64;
        VMCNT(2); BAR();
        g2_stage_G0(A, Bt, Anxt, Bnxt, m0, n0, K, kc1, w, lane);
        g2_phase(Acur, Bcur, acc, wr, wc, lane, 0, 0);
        VMCNT(3); BAR();
        g2_phase(Acur, Bcur, acc, wr, wc, lane, 0, 1);
        VMCNT(2); BAR();
        g2_stage_G1(A, Bt, Anxt, Bnxt, m0, n0, K, kc1, w, lane);
        g2_phase(Acur, Bcur, acc, wr, wc, lane, 1, 0);
        g2_phase(Acur, Bcur, acc, wr, wc, lane, 1, 1);
    }
    {
        const int p = (NT - 1) & 1;
        ushort* Acur = lds + p * 8192;
        ushort* Bcur = lds + 16384 + p * 8192;
        VMCNT(2); BAR();
        g2_phase(Acur, Bcur, acc, wr, wc, lane, 0, 0);
        VMCNT(1); BAR();
        g2_phase(Acur, Bcur, acc, wr, wc, lane, 0, 1);
        VMCNT(0); BAR();
        g2_phase(Acur, Bcur, acc, wr, wc, lane, 1, 0);
        g2_phase(Acur, Bcur, acc, wr, wc, lane, 1, 1);
    }

    const int crow = (lane >> 4) * 4, ccol = lane & 15;
#pragma unroll
    for (int nj = 0; nj < 2; ++nj) {
        int col = n0 + wc + nj * 16 + ccol;
        float bv = bias[col];
#pragma unroll
        for (int mi = 0; mi < 4; ++mi) {
#pragma unroll
            for (int rr = 0; rr < 4; ++rr) {
                int row = m0 + wr + mi * 16 + crow + rr;
                Cout[(size_t)row * N + col] = acc[mi][nj][rr] + bv;
            }
        }
    }
}

// ---------------- chunk_kv: transpose K,V per chunk; St(bf16) = Vt@Kt^T; sK sums ----------------
__global__ __launch_bounds__(256) void chunk_kv_mfma(
    const ushort* __restrict__ out1, ushort* __restrict__ VtG,
    ushort* __restrict__ StB, float* __restrict__ sks)
{
    __shared__ unsigned Tl[64 * 76];
    __shared__ ushort Ktb[64 * 64];
    __shared__ ushort Vtb[64 * 64];
    __shared__ float skp[4][64];
    const int blk = blockIdx.x, c = blk & 31, bh = blk >> 5;
    const int b = bh >> 4, h = bh & 15, t0 = c * CH_;
    const int tid = threadIdx.x, wave = tid >> 6, lane = tid & 63;
    const ushort* kg = out1 + (size_t)(b * T_ + t0) * 3072 + C_ + h * D_;
    const ushort* vg = kg + C_;

#pragma unroll
    for (int it = 0; it < 2; ++it) {
        int i = tid + it * 256, r = i >> 3, sl = i & 7;
        bf16x8 v = *(const bf16x8*)(kg + (size_t)r * 3072 + sl * 8);
        unsigned* dst = &Tl[r * 76 + sl * 8];
        uint4 w0 = { (ushort)v[0], (ushort)v[1], (ushort)v[2], (ushort)v[3] };
        uint4 w1 = { (ushort)v[4], (ushort)v[5], (ushort)v[6], (ushort)v[7] };
        *(uint4*)dst = w0;
        *(uint4*)(dst + 4) = w1;
    }
    __syncthreads();
    {
        int m = tid >> 2, tc = tid & 3;
        bf16x8 va, vb;
        float s = 0.f;
#pragma unroll
        for (int k = 0; k < 8; ++k) {
            ushort u = (ushort)Tl[(tc * 16 + k) * 76 + m];
            va[k] = (short)u; s += bf2f(u);
        }
#pragma unroll
        for (int k = 0; k < 8; ++k) {
            ushort u = (ushort)Tl[(tc * 16 + 8 + k) * 76 + m];
            vb[k] = (short)u; s += bf2f(u);
        }
        skp[tc][m] = s;
        int b0 = (tc * 32) ^ ((m & 7) << 4);
        int b1 = (tc * 32 + 16) ^ ((m & 7) << 4);
        *(bf16x8*)((char*)Ktb + m * 128 + b0) = va;
        *(bf16x8*)((char*)Ktb + m * 128 + b1) = vb;
    }
    __syncthreads();
#pragma unroll
    for (int it = 0; it < 2; ++it) {
        int i = tid + it * 256, r = i >> 3, sl = i & 7;
        bf16x8 v = *(const bf16x8*)(vg + (size_t)r * 3072 + sl * 8);
        unsigned* dst = &Tl[r * 76 + sl * 8];
        uint4 w0 = { (ushort)v[0], (ushort)v[1], (ushort)v[2], (ushort)v[3] };
        uint4 w1 = { (ushort)v[4], (ushort)v[5], (ushort)v[6], (ushort)v[7] };
        *(uint4*)dst = w0;
        *(uint4*)(dst + 4) = w1;
    }
    __syncthreads();
    {
        int d = tid >> 2, tc = tid & 3;
        bf16x8 va, vb;
#pragma unroll
        for (int k = 0; k < 8; ++k) va[k] = (short)(ushort)Tl[(tc * 16 + k) * 76 + d];
#pragma unroll
        for (int k = 0; k < 8; ++k) vb[k] = (short)(ushort)Tl[(tc * 16 + 8 + k) * 76 + d];
        int b0 = (tc * 32) ^ ((d & 7) << 4);
        int b1 = (tc * 32 + 16) ^ ((d & 7) << 4);
        *(bf16x8*)((char*)Vtb + d * 128 + b0) = va;
        *(bf16x8*)((char*)Vtb + d * 128 + b1) = vb;
        ushort* og = VtG + (size_t)blk * 4096 + d * 64 + tc * 16;
        *(bf16x8*)og = va;
        *(bf16x8*)(og + 8) = vb;
    }
    __syncthreads();
    const int wr = wave * 16, g = lane >> 4, ccol = lane & 15;
    f32x4 acc[4] = {};
#pragma unroll
    for (int k0 = 0; k0 < 64; k0 += 32) {
        bf16x8 av = frag_ld(Vtb, wr, k0, lane);
#pragma unroll
        for (int j = 0; j < 4; ++j)
            acc[j] = __builtin_amdgcn_mfma_f32_16x16x32_bf16(av, frag_ld(Ktb, j * 16, k0, lane), acc[j], 0, 0, 0);
    }
    ushort* stg = StB + (size_t)blk * 4096;
#pragma unroll
    for (int j = 0; j < 4; ++j)
#pragma unroll
        for (int r = 0; r < 4; ++r)
            stg[(wr + g * 4 + r) * 64 + j * 16 + ccol] = f2bf(acc[j][r]);
    if (tid < 64)
        sks[(size_t)blk * 64 + tid] = skp[0][tid] + skp[1][tid] + skp[2][tid] + skp[3][tid];
}

// ---------------- parallel exclusive chunk-prefix scan (St bf16) ----------------
__global__ __launch_bounds__(256) void chunk_scan2(const ushort* __restrict__ StB,
                                                   const float* __restrict__ sks,
                                                   ushort* __restrict__ Sbf,
                                                   ushort* __restrict__ skb) {
    if (blockIdx.x < 512) {
        int id = blockIdx.x * 256 + threadIdx.x;
        int bh = id >> 12, e = id & 4095;
        const ushort* p = StB + (size_t)bh * NC_ * 4096 + e;
        ushort* q = Sbf + (size_t)bh * NC_ * 4096 + e;
        float run = 0.f;
        for (int c = 0; c < NC_; ++c) {
            q[(size_t)c * 4096] = f2bf(run);
            run += bf2f(p[(size_t)c * 4096]);
        }
    } else {
        int id2 = (blockIdx.x - 512) * 256 + threadIdx.x;
        int bh = id2 >> 6, m = id2 & 63;
        const float* p = sks + (size_t)bh * NC_ * 64 + m;
        ushort* q = skb + (size_t)bh * NC_ * 64 + m;
        float run = 0.f;
        for (int c = 0; c < NC_; ++c) {
            q[c * 64] = f2bf(run);
            run += p[c * 64];
        }
    }
}

// ---------------- chunk attention (all-MFMA) ----------------
__global__ __launch_bounds__(256) void chunk_attn_mfma(
    const ushort* __restrict__ out1, const ushort* __restrict__ VtG,
    const ushort* __restrict__ Sbf, const ushort* __restrict__ skb,
    ushort* __restrict__ attnBf)
{
    __shared__ ushort Ql[64 * 64];
    __shared__ ushort Kl[64 * 64];
    __shared__ ushort Vl[64 * 64];
    __shared__ ushort Al[64 * 64];
    __shared__ ushort Sl[80 * 64];
    const int blk = blockIdx.x, c = blk & 31, bh = blk >> 5;
    const int b = bh >> 4, h = bh & 15, t0 = c * CH_;
    const int tid = threadIdx.x, wave = tid >> 6, lane = tid & 63;
    const ushort* qg  = out1 + (size_t)(b * T_ + t0) * 3072 + h * D_;
    const ushort* kg  = qg + C_;
    const ushort* vtg = VtG + (size_t)blk * 4096;
    const ushort* sbg = Sbf + (size_t)blk * 4096;
#pragma unroll
    for (int it = 0; it < 2; ++it) {
        int i = tid + it * 256, r = i >> 3, sl = i & 7;
        int lo = (sl * 16) ^ ((r & 7) << 4);
        *(bf16x8*)((char*)Ql + r * 128 + lo) = *(const bf16x8*)(qg + (size_t)r * 3072 + sl * 8);
        *(bf16x8*)((char*)Kl + r * 128 + lo) = *(const bf16x8*)(kg + (size_t)r * 3072 + sl * 8);
        *(bf16x8*)((char*)Vl + r * 128 + lo) = *(const bf16x8*)(vtg + r * 64 + sl * 8);
        *(bf16x8*)((char*)Sl + r * 128 + lo) = *(const bf16x8*)(sbg + r * 64 + sl * 8);
    }
    if (tid < 8)
        *(bf16x8*)((char*)Sl + 64 * 128 + tid * 16) = *(const bf16x8*)(skb + (size_t)blk * 64 + tid * 8);
    __syncthreads();

    const int wr = wave * 16, g = lane >> 4, ccol = lane & 15;
    f32x4 accA[4] = {};
#pragma unroll
    for (int k0 = 0; k0 < 64; k0 += 32) {
        bf16x8 aq = frag_ld(Ql, wr, k0, lane);
#pragma unroll
        for (int j = 0; j < 4; ++j)
            accA[j] = __builtin_amdgcn_mfma_f32_16x16x32_bf16(aq, frag_ld(Kl, j * 16, k0, lane), accA[j], 0, 0, 0);
    }
    float rsum[4] = {0.f, 0.f, 0.f, 0.f};
#pragma unroll
    for (int j = 0; j < 4; ++j) {
#pragma unroll
        for (int r = 0; r < 4; ++r) {
            int tl = wr + g * 4 + r, sl2 = j * 16 + ccol;
            float v = (sl2 <= tl) ? accA[j][r] : 0.f;
            rsum[r] += v;
            *(ushort*)((char*)Al + tl * 128 + ((sl2 * 2) ^ ((tl & 7) << 4))) = f2bf(v);
        }
    }
#pragma unroll
    for (int r = 0; r < 4; ++r) {
        rsum[r] += __shfl_xor(rsum[r], 1);
        rsum[r] += __shfl_xor(rsum[r], 2);
        rsum[r] += __shfl_xor(rsum[r], 4);
        rsum[r] += __shfl_xor(rsum[r], 8);
    }
    f32x4 accC[4] = {};
    f32x4 accE = {};
#pragma unroll
    for (int k0 = 0; k0 < 64; k0 += 32) {
        bf16x8 aa = frag_ld(Al, wr, k0, lane);
#pragma unroll
        for (int j = 0; j < 4; ++j)
            accC[j] = __builtin_amdgcn_mfma_f32_16x16x32_bf16(aa, frag_ld(Vl, j * 16, k0, lane), accC[j], 0, 0, 0);
    }
#pragma unroll
    for (int k0 = 0; k0 < 64; k0 += 32) {
        bf16x8 aq = frag_ld(Ql, wr, k0, lane);
#pragma unroll
        for (int j = 0; j < 4; ++j)
            accC[j] = __builtin_amdgcn_mfma_f32_16x16x32_bf16(aq, frag_ld(Sl, j * 16, k0, lane), accC[j], 0, 0, 0);
        accE = __builtin_amdgcn_mfma_f32_16x16x32_bf16(aq, frag_ld(Sl, 64, k0, lane), accE, 0, 0, 0);
    }
    ushort* og = attnBf + (size_t)(b * T_ + t0) * C_ + h * D_;
#pragma unroll
    for (int r = 0; r < 4; ++r) {
        float nq = __shfl(accE[r], (lane & 48));
        float inv = 1.f / (nq + rsum[r] + 1e-6f);
        int tl = wr + g * 4 + r;
#pragma unroll
        for (int j = 0; j < 4; ++j)
            og[(size_t)tl * C_ + j * 16 + ccol] = f2bf(accC[j][r] * inv);
    }
}

extern "C" void kernel_launch(void* const* d_in, const int* in_sizes, int n_in,
                              void* d_out, int out_size, void* d_ws, size_t ws_size,
                              hipStream_t stream) {
    (void)in_sizes; (void)n_in; (void)out_size; (void)ws_size;
    const float* x    = (const float*)d_in[0];
    const float* Wqkv = (const float*)d_in[1];
    const float* bqkv = (const float*)d_in[2];
    const float* Wout = (const float*)d_in[3];
    const float* bout = (const float*)d_in[4];
    const float* proj = (const float*)d_in[5];
    float* out = (float*)d_out;
    char* ws = (char*)d_ws;

    ushort* Wbt    = (ushort*)(ws);                 // 6 MB
    ushort* xbf    = (ushort*)(ws + (6ull  << 20)); // 8 MB
    ushort* WoutBf = (ushort*)(ws + (14ull << 20)); // 2 MB
    ushort* attnBf = (ushort*)(ws + (16ull << 20)); // 8 MB
    float*  bbig   = (float*) (ws + (24ull << 20)); // 12 KB
    ushort* out1   = (ushort*)(ws + (25ull << 20)); // 24 MB (bf16 q'|k'|v)
    ushort* VtG    = (ushort*)(ws + (49ull << 20)); // 8 MB
    ushort* StB    = (ushort*)(ws + (57ull << 20)); // 8 MB (bf16)
    ushort* Sbf    = (ushort*)(ws + (65ull << 20)); // 8 MB
    float*  sks    = (float*) (ws + (73ull << 20)); // 256 KB
    ushort* skb    = (ushort*)(ws + (74ull << 20)); // 128 KB

    prep_all<<<NPREP_, 256, 0, stream>>>(x, Wqkv, bqkv, Wout, proj,
                                         Wbt, xbf, WoutBf, bbig);
    gemm_8phase<<<dim3(8, 32), 512, 0, stream>>>(xbf, Wbt, bbig, out1,
                                                 4096, 3072, 1024, 2048);
    chunk_kv_mfma<<<1024, 256, 0, stream>>>(out1, VtG, StB, sks);
    chunk_scan2<<<520, 256, 0, stream>>>(StB, sks, Sbf, skb);
    chunk_attn_mfma<<<1024, 256, 0, stream>>>(out1, VtG, Sbf, skb, attnBf);
    gemm2_8phase<<<dim3(8, 32), 512, 0, stream>>>(attnBf, WoutBf, bout, out,
                                                  4096, 1024, 1024);
}

// Round 9
// 85.553 us; speedup vs baseline: 7.0247x; 1.0379x over previous
//
#include <hip/hip_runtime.h>
#include <cstddef>

#define B_  2
#define T_  2048
#define C_  1024
#define H_  16
#define D_  64
#define M_  64
#define NC_ 32
#define CH_ 64

typedef __attribute__((ext_vector_type(8))) short bf16x8;
typedef __attribute__((ext_vector_type(4))) float f32x4;

__device__ __forceinline__ ushort f2bf(float f) {
    union { float f; unsigned u; } v; v.f = f;
    unsigned r = v.u + 0x7FFF + ((v.u >> 16) & 1);   // RNE
    return (ushort)(r >> 16);
}
__device__ __forceinline__ float bf2f(ushort u) {
    union { unsigned u; float f; } x; x.u = ((unsigned)u) << 16; return x.f;
}

__device__ __forceinline__ void gld_lds16(const ushort* g, ushort* lds) {
    __builtin_amdgcn_global_load_lds(
        (const __attribute__((address_space(1))) unsigned int*)g,
        (__attribute__((address_space(3))) unsigned int*)lds,
        16, 0, 0);
}

// fragment read from a swizzled [R][64] bf16 LDS tile (128B rows, byte ^= (row&7)<<4)
__device__ __forceinline__ bf16x8 frag_ld(const ushort* lds, int row16, int k0, int lane) {
    int r = row16 + (lane & 15);
    int byte = ((k0 * 2) + ((lane >> 4) << 4)) ^ ((r & 7) << 4);
    return *(const bf16x8*)((const char*)lds + r * 128 + byte);
}

#define VMCNT(n) asm volatile("s_waitcnt vmcnt(" #n ")" ::: "memory")
#define BAR() do { __builtin_amdgcn_s_barrier(); __builtin_amdgcn_sched_barrier(0); } while (0)

// ================= fused prep: weight combine + casts + bias =================
#define SEG1_ 256
#define SEG2_ 512
#define SEG3_ 1536
#define SEG4_ 1792
#define NPREP_ 1804

__global__ __launch_bounds__(256) void prep_all(
    const float* __restrict__ x, const float* __restrict__ Wqkv,
    const float* __restrict__ bqkv, const float* __restrict__ Wout,
    const float* __restrict__ proj,
    ushort* __restrict__ Wbt, ushort* __restrict__ xbf,
    ushort* __restrict__ WoutBf, float* __restrict__ bbig)
{
    __shared__ float Ws[64 * 128];
    __shared__ float Ps[64 * 64];
    const int blk = blockIdx.x, t = threadIdx.x;
    if (blk < SEG1_) {
        const int sel = blk >> 7, h = (blk >> 3) & 15, cc = blk & 7;
        const int rowbase = sel * 1024 + h * 64;
        {
            const int r0 = t >> 5, cq = t & 31;
#pragma unroll
            for (int k = 0; k < 8; ++k) {
                int r = r0 + 8 * k;
                *(float4*)&Ws[r * 128 + cq * 4] =
                    *(const float4*)&Wqkv[(size_t)(rowbase + r) * 1024 + cc * 128 + cq * 4];
            }
        }
#pragma unroll
        for (int k = 0; k < 4; ++k) {
            int i4 = t + 256 * k;
            *(float4*)&Ps[i4 * 4] = *(const float4*)&proj[h * 4096 + i4 * 4];
        }
        __syncthreads();
#pragma unroll
        for (int k = 0; k < 2; ++k) {
            int id = t + 256 * k;
            int m4 = id >> 5, c4 = id & 31;
            float4 a0 = {0.f,0.f,0.f,0.f}, a1 = a0, a2 = a0, a3 = a0;
            for (int d = 0; d < 64; ++d) {
                float4 w = *(const float4*)&Ws[d * 128 + c4 * 4];
                float4 p = *(const float4*)&Ps[d * 64 + m4 * 4];
                a0.x += p.x*w.x; a0.y += p.x*w.y; a0.z += p.x*w.z; a0.w += p.x*w.w;
                a1.x += p.y*w.x; a1.y += p.y*w.y; a1.z += p.y*w.z; a1.w += p.y*w.w;
                a2.x += p.z*w.x; a2.y += p.z*w.y; a2.z += p.z*w.z; a2.w += p.z*w.w;
                a3.x += p.w*w.x; a3.y += p.w*w.y; a3.z += p.w*w.z; a3.w += p.w*w.w;
            }
            size_t obase = (size_t)(rowbase + m4 * 4) * 1024 + cc * 128 + c4 * 4;
            ushort4 o0 = { f2bf(a0.x), f2bf(a0.y), f2bf(a0.z), f2bf(a0.w) };
            ushort4 o1 = { f2bf(a1.x), f2bf(a1.y), f2bf(a1.z), f2bf(a1.w) };
            ushort4 o2 = { f2bf(a2.x), f2bf(a2.y), f2bf(a2.z), f2bf(a2.w) };
            ushort4 o3 = { f2bf(a3.x), f2bf(a3.y), f2bf(a3.z), f2bf(a3.w) };
            *(ushort4*)&Wbt[obase]          = o0;
            *(ushort4*)&Wbt[obase + 1024]   = o1;
            *(ushort4*)&Wbt[obase + 2048]   = o2;
            *(ushort4*)&Wbt[obase + 3072]   = o3;
        }
    } else if (blk < SEG2_) {
        int bo = blk - SEG1_;
#pragma unroll
        for (int pass = 0; pass < 4; ++pass) {
            int i4 = bo * 1024 + pass * 256 + t;
            float4 v = ((const float4*)Wqkv)[524288 + i4];
            ushort4 o = { f2bf(v.x), f2bf(v.y), f2bf(v.z), f2bf(v.w) };
            ((ushort4*)(Wbt + 2097152))[i4] = o;
        }
    } else if (blk < SEG3_) {
        int bo = blk - SEG2_;
#pragma unroll
        for (int pass = 0; pass < 4; ++pass) {
            int i4 = bo * 1024 + pass * 256 + t;
            float4 v = ((const float4*)x)[i4];
            ushort4 o = { f2bf(v.x), f2bf(v.y), f2bf(v.z), f2bf(v.w) };
            ((ushort4*)xbf)[i4] = o;
        }
    } else if (blk < SEG4_) {
        int bo = blk - SEG3_;
#pragma unroll
        for (int pass = 0; pass < 4; ++pass) {
            int i4 = bo * 1024 + pass * 256 + t;
            float4 v = ((const float4*)Wout)[i4];
            ushort4 o = { f2bf(v.x), f2bf(v.y), f2bf(v.z), f2bf(v.w) };
            ((ushort4*)WoutBf)[i4] = o;
        }
    } else {
        int j = (blk - SEG4_) * 256 + t;
        if (j < 2048) {
            int sel = j >> 10, hm = j & 1023, h = hm >> 6, m = hm & 63;
            const float* b = bqkv + sel * C_ + h * D_;
            const float* p = proj + (size_t)h * D_ * M_ + m;
            float acc = 0.f;
#pragma unroll 8
            for (int d = 0; d < D_; ++d) acc += b[d] * p[(size_t)d * M_];
            bbig[j] = acc;
        } else {
            bbig[j] = bqkv[j];
        }
    }
}

// ================= 8-phase pipelined GEMM1 (BM=128, BN=384, BK=64) =================
// Fragment-hoisted: each LDS fragment read exactly once per K-tile.
__device__ __forceinline__ void stage_G0(const ushort* __restrict__ Ag, const ushort* __restrict__ Bg,
                                         ushort* Abuf, ushort* Bbuf,
                                         int m0, int n0, int K, int kcol, int w, int lane) {
    const int l8 = lane >> 3, lc = (lane & 7) * 8;
#pragma unroll
    for (int i = 0; i < 4; ++i) {
        int c = w * 4 + i;
        if (c < 8) {
            int fr = (c < 4) ? c * 8 : 64 + (c - 4) * 8;
            int r = fr + l8;
            int cs = lc ^ ((r & 7) << 3);
            gld_lds16(Ag + (size_t)(m0 + r) * K + kcol + cs, Abuf + fr * 64);
        } else {
            int cb = c - 8, g = cb / 6, k8 = cb - g * 6;
            int fr = g * 96 + k8 * 8;
            int r = fr + l8;
            int cs = lc ^ ((r & 7) << 3);
            gld_lds16(Bg + (size_t)(n0 + r) * K + kcol + cs, Bbuf + fr * 64);
        }
    }
}

__device__ __forceinline__ void stage_G1(const ushort* __restrict__ Ag, const ushort* __restrict__ Bg,
                                         ushort* Abuf, ushort* Bbuf,
                                         int m0, int n0, int K, int kcol, int w, int lane) {
    const int l8 = lane >> 3, lc = (lane & 7) * 8;
#pragma unroll
    for (int i = 0; i < 3; ++i) {
        int cb = w * 3 + i, g = cb / 6, k8 = cb - g * 6;
        int fr = g * 96 + 48 + k8 * 8;
        int r = fr + l8;
        int cs = lc ^ ((r & 7) << 3);
        gld_lds16(Bg + (size_t)(n0 + r) * K + kcol + cs, Bbuf + fr * 64);
    }
    {
        int fr = (w < 4) ? 32 + w * 8 : 96 + (w - 4) * 8;
        int r = fr + l8;
        int cs = lc ^ ((r & 7) << 3);
        gld_lds16(Ag + (size_t)(m0 + r) * K + kcol + cs, Abuf + fr * 64);
    }
}

__device__ __forceinline__ void lda2(const ushort* Abuf, bf16x8 (&a)[2][2], int wr, int Mh, int lane) {
#pragma unroll
    for (int i = 0; i < 2; ++i)
#pragma unroll
        for (int ks = 0; ks < 2; ++ks)
            a[i][ks] = frag_ld(Abuf, wr + Mh * 32 + i * 16, ks * 32, lane);
}
__device__ __forceinline__ void ldb3(const ushort* Bbuf, bf16x8 (&b)[3][2], int wc, int Nh, int lane) {
#pragma unroll
    for (int j = 0; j < 3; ++j)
#pragma unroll
        for (int ks = 0; ks < 2; ++ks)
            b[j][ks] = frag_ld(Bbuf, wc + Nh * 48 + j * 16, ks * 32, lane);
}
__device__ __forceinline__ void mfma6(f32x4 (&acc)[4][6], const bf16x8 (&a)[2][2],
                                      const bf16x8 (&b)[3][2], int Mh, int Nh) {
    __builtin_amdgcn_s_setprio(1);
#pragma unroll
    for (int ks = 0; ks < 2; ++ks)
#pragma unroll
        for (int i = 0; i < 2; ++i)
#pragma unroll
            for (int j = 0; j < 3; ++j)
                acc[Mh * 2 + i][Nh * 3 + j] = __builtin_amdgcn_mfma_f32_16x16x32_bf16(
                    a[i][ks], b[j][ks], acc[Mh * 2 + i][Nh * 3 + j], 0, 0, 0);
    __builtin_amdgcn_s_setprio(0);
}

__global__ __launch_bounds__(512) void gemm_8phase(
    const ushort* __restrict__ A, const ushort* __restrict__ Bt,
    const float* __restrict__ bias, ushort* __restrict__ Cout,
    int M, int N, int K, int reluLimit)
{
    __shared__ __align__(16) ushort lds[65536];

    const int tid = threadIdx.x, w = tid >> 6, lane = tid & 63;
    const int m0 = blockIdx.y * 128, n0 = blockIdx.x * 384;
    const int wr = (w >> 2) * 64, wc = (w & 3) * 96;
    f32x4 acc[4][6] = {};
    const int NT = K / 64;

    stage_G0(A, Bt, lds, lds + 16384, m0, n0, K, 0, w, lane);
    stage_G1(A, Bt, lds, lds + 16384, m0, n0, K, 0, w, lane);

    for (int kt = 0; kt < NT - 1; ++kt) {
        const int p = kt & 1;
        ushort* Acur = lds + p * 8192;
        ushort* Anxt = lds + (p ^ 1) * 8192;
        ushort* Bcur = lds + 16384 + p * 24576;
        ushort* Bnxt = lds + 16384 + (p ^ 1) * 24576;
        const int kc1 = (kt + 1) * 64;
        bf16x8 a[2][2], a2[2][2], b[3][2], b2[3][2];
        VMCNT(4); BAR();
        stage_G0(A, Bt, Anxt, Bnxt, m0, n0, K, kc1, w, lane);
        lda2(Acur, a, wr, 0, lane);
        ldb3(Bcur, b, wc, 0, lane);
        mfma6(acc, a, b, 0, 0);
        VMCNT(5); BAR();
        ldb3(Bcur, b2, wc, 1, lane);
        mfma6(acc, a, b2, 0, 1);
        VMCNT(4); BAR();
        stage_G1(A, Bt, Anxt, Bnxt, m0, n0, K, kc1, w, lane);
        lda2(Acur, a2, wr, 1, lane);
        mfma6(acc, a2, b, 1, 0);
        mfma6(acc, a2, b2, 1, 1);
    }
    {
        const int p = (NT - 1) & 1;
        ushort* Acur = lds + p * 8192;
        ushort* Bcur = lds + 16384 + p * 24576;
        bf16x8 a[2][2], a2[2][2], b[3][2], b2[3][2];
        VMCNT(4); BAR();
        lda2(Acur, a, wr, 0, lane);
        ldb3(Bcur, b, wc, 0, lane);
        mfma6(acc, a, b, 0, 0);
        VMCNT(1); BAR();
        ldb3(Bcur, b2, wc, 1, lane);
        mfma6(acc, a, b2, 0, 1);
        VMCNT(0); BAR();
        lda2(Acur, a2, wr, 1, lane);
        mfma6(acc, a2, b, 1, 0);
        mfma6(acc, a2, b2, 1, 1);
    }

    const int crow = (lane >> 4) * 4, ccol = lane & 15;
#pragma unroll
    for (int nj = 0; nj < 6; ++nj) {
        int col = n0 + wc + nj * 16 + ccol;
        float bv = bias[col];
        bool rl = col < reluLimit;
#pragma unroll
        for (int mi = 0; mi < 4; ++mi) {
#pragma unroll
            for (int rr = 0; rr < 4; ++rr) {
                int row = m0 + wr + mi * 16 + crow + rr;
                float v = acc[mi][nj][rr] + bv;
                if (rl) v = fmaxf(v, 0.f);
                Cout[(size_t)row * N + col] = f2bf(v);
            }
        }
    }
}

// ================= 8-phase GEMM2 (BM=128, BN=128, BK=64, 2 blocks/CU), fragment-hoisted =================
__device__ __forceinline__ void g2_stage_G0(const ushort* __restrict__ Ag, const ushort* __restrict__ Bg,
                                            ushort* Abuf, ushort* Bbuf,
                                            int m0, int n0, int K, int kcol, int w, int lane) {
    const int l8 = lane >> 3, lc = (lane & 7) * 8;
    {
        int rbase = (w < 4) ? w * 8 : 64 + (w - 4) * 8;
        int r = rbase + l8;
        int cs = lc ^ ((r & 7) << 3);
        gld_lds16(Ag + (size_t)(m0 + r) * K + kcol + cs, Abuf + rbase * 64);
    }
    {
        int rbase = (w >> 1) * 32 + (w & 1) * 8;
        int r = rbase + l8;
        int cs = lc ^ ((r & 7) << 3);
        gld_lds16(Bg + (size_t)(n0 + r) * K + kcol + cs, Bbuf + rbase * 64);
    }
}

__device__ __forceinline__ void g2_stage_G1(const ushort* __restrict__ Ag, const ushort* __restrict__ Bg,
                                            ushort* Abuf, ushort* Bbuf,
                                            int m0, int n0, int K, int kcol, int w, int lane) {
    const int l8 = lane >> 3, lc = (lane & 7) * 8;
    {   // B rows {16-31,48-63,80-95,112-127}
        int rbase = 16 + (w >> 1) * 32 + (w & 1) * 8;
        int r = rbase + l8;
        int cs = lc ^ ((r & 7) << 3);
        gld_lds16(Bg + (size_t)(n0 + r) * K + kcol + cs, Bbuf + rbase * 64);
    }
    {   // A rows {32-63, 96-127}
        int rbase = (w < 4) ? 32 + w * 8 : 96 + (w - 4) * 8;
        int r = rbase + l8;
        int cs = lc ^ ((r & 7) << 3);
        gld_lds16(Ag + (size_t)(m0 + r) * K + kcol + cs, Abuf + rbase * 64);
    }
}

__device__ __forceinline__ void g2_ldb(const ushort* Bbuf, bf16x8 (&b)[2], int wc, int Nh, int lane) {
#pragma unroll
    for (int ks = 0; ks < 2; ++ks)
        b[ks] = frag_ld(Bbuf, wc + Nh * 16, ks * 32, lane);
}
__device__ __forceinline__ void g2_mfma(f32x4 (&acc)[4][2], const bf16x8 (&a)[2][2],
                                        const bf16x8 (&b)[2], int Mh, int Nh) {
    __builtin_amdgcn_s_setprio(1);
#pragma unroll
    for (int ks = 0; ks < 2; ++ks)
#pragma unroll
        for (int i = 0; i < 2; ++i)
            acc[Mh * 2 + i][Nh] = __builtin_amdgcn_mfma_f32_16x16x32_bf16(
                a[i][ks], b[ks], acc[Mh * 2 + i][Nh], 0, 0, 0);
    __builtin_amdgcn_s_setprio(0);
}

__global__ __launch_bounds__(512, 4) void gemm2_8phase(
    const ushort* __restrict__ A, const ushort* __restrict__ Bt,
    const float* __restrict__ bias, float* __restrict__ Cout,
    int M, int N, int K)
{
    __shared__ __align__(16) ushort lds[32768];      // 64 KiB

    const int tid = threadIdx.x, w = tid >> 6, lane = tid & 63;
    const int m0 = blockIdx.y * 128, n0 = blockIdx.x * 128;
    const int wr = (w >> 2) * 64, wc = (w & 3) * 32;
    f32x4 acc[4][2] = {};
    const int NT = K / 64;

    g2_stage_G0(A, Bt, lds, lds + 16384, m0, n0, K, 0, w, lane);
    g2_stage_G1(A, Bt, lds, lds + 16384, m0, n0, K, 0, w, lane);

    for (int kt = 0; kt < NT - 1; ++kt) {
        const int p = kt & 1;
        ushort* Acur = lds + p * 8192;
        ushort* Anxt = lds + (p ^ 1) * 8192;
        ushort* Bcur = lds + 16384 + p * 8192;
        ushort* Bnxt = lds + 16384 + (p ^ 1) * 8192;
        const int kc1 = (kt + 1) * 64;
        bf16x8 a[2][2], a2[2][2], b[2], b2[2];
        VMCNT(2); BAR();
        g2_stage_G0(A, Bt, Anxt, Bnxt, m0, n0, K, kc1, w, lane);
        lda2(Acur, a, wr, 0, lane);
        g2_ldb(Bcur, b, wc, 0, lane);
        g2_mfma(acc, a, b, 0, 0);
        VMCNT(3); BAR();
        g2_ldb(Bcur, b2, wc, 1, lane);
        g2_mfma(acc, a, b2, 0, 1);
        VMCNT(2); BAR();
        g2_stage_G1(A, Bt, Anxt, Bnxt, m0, n0, K, kc1, w, lane);
        lda2(Acur, a2, wr, 1, lane);
        g2_mfma(acc, a2, b, 1, 0);
        g2_mfma(acc, a2, b2, 1, 1);
    }
    {
        const int p = (NT - 1) & 1;
        ushort* Acur = lds + p * 8192;
        ushort* Bcur = lds + 16384 + p * 8192;
        bf16x8 a[2][2], a2[2][2], b[2], b2[2];
        VMCNT(2); BAR();
        lda2(Acur, a, wr, 0, lane);
        g2_ldb(Bcur, b, wc, 0, lane);
        g2_mfma(acc, a, b, 0, 0);
        VMCNT(1); BAR();
        g2_ldb(Bcur, b2, wc, 1, lane);
        g2_mfma(acc, a, b2, 0, 1);
        VMCNT(0); BAR();
        lda2(Acur, a2, wr, 1, lane);
        g2_mfma(acc, a2, b, 1, 0);
        g2_mfma(acc, a2, b2, 1, 1);
    }

    const int crow = (lane >> 4) * 4, ccol = lane & 15;
#pragma unroll
    for (int nj = 0; nj < 2; ++nj) {
        int col = n0 + wc + nj * 16 + ccol;
        float bv = bias[col];
#pragma unroll
        for (int mi = 0; mi < 4; ++mi) {
#pragma unroll
            for (int rr = 0; rr < 4; ++rr) {
                int row = m0 + wr + mi * 16 + crow + rr;
                Cout[(size_t)row * N + col] = acc[mi][nj][rr] + bv;
            }
        }
    }
}

// ---------------- chunk_kv: transpose K,V per chunk; St(bf16) = Vt@Kt^T; sK sums ----------------
__global__ __launch_bounds__(256) void chunk_kv_mfma(
    const ushort* __restrict__ out1, ushort* __restrict__ VtG,
    ushort* __restrict__ StB, float* __restrict__ sks)
{
    __shared__ unsigned Tl[64 * 76];
    __shared__ ushort Ktb[64 * 64];
    __shared__ ushort Vtb[64 * 64];
    __shared__ float skp[4][64];
    const int blk = blockIdx.x, c = blk & 31, bh = blk >> 5;
    const int b = bh >> 4, h = bh & 15, t0 = c * CH_;
    const int tid = threadIdx.x, wave = tid >> 6, lane = tid & 63;
    const ushort* kg = out1 + (size_t)(b * T_ + t0) * 3072 + C_ + h * D_;
    const ushort* vg = kg + C_;

#pragma unroll
    for (int it = 0; it < 2; ++it) {
        int i = tid + it * 256, r = i >> 3, sl = i & 7;
        bf16x8 v = *(const bf16x8*)(kg + (size_t)r * 3072 + sl * 8);
        unsigned* dst = &Tl[r * 76 + sl * 8];
        uint4 w0 = { (ushort)v[0], (ushort)v[1], (ushort)v[2], (ushort)v[3] };
        uint4 w1 = { (ushort)v[4], (ushort)v[5], (ushort)v[6], (ushort)v[7] };
        *(uint4*)dst = w0;
        *(uint4*)(dst + 4) = w1;
    }
    __syncthreads();
    {
        int m = tid >> 2, tc = tid & 3;
        bf16x8 va, vb;
        float s = 0.f;
#pragma unroll
        for (int k = 0; k < 8; ++k) {
            ushort u = (ushort)Tl[(tc * 16 + k) * 76 + m];
            va[k] = (short)u; s += bf2f(u);
        }
#pragma unroll
        for (int k = 0; k < 8; ++k) {
            ushort u = (ushort)Tl[(tc * 16 + 8 + k) * 76 + m];
            vb[k] = (short)u; s += bf2f(u);
        }
        skp[tc][m] = s;
        int b0 = (tc * 32) ^ ((m & 7) << 4);
        int b1 = (tc * 32 + 16) ^ ((m & 7) << 4);
        *(bf16x8*)((char*)Ktb + m * 128 + b0) = va;
        *(bf16x8*)((char*)Ktb + m * 128 + b1) = vb;
    }
    __syncthreads();
#pragma unroll
    for (int it = 0; it < 2; ++it) {
        int i = tid + it * 256, r = i >> 3, sl = i & 7;
        bf16x8 v = *(const bf16x8*)(vg + (size_t)r * 3072 + sl * 8);
        unsigned* dst = &Tl[r * 76 + sl * 8];
        uint4 w0 = { (ushort)v[0], (ushort)v[1], (ushort)v[2], (ushort)v[3] };
        uint4 w1 = { (ushort)v[4], (ushort)v[5], (ushort)v[6], (ushort)v[7] };
        *(uint4*)dst = w0;
        *(uint4*)(dst + 4) = w1;
    }
    __syncthreads();
    {
        int d = tid >> 2, tc = tid & 3;
        bf16x8 va, vb;
#pragma unroll
        for (int k = 0; k < 8; ++k) va[k] = (short)(ushort)Tl[(tc * 16 + k) * 76 + d];
#pragma unroll
        for (int k = 0; k < 8; ++k) vb[k] = (short)(ushort)Tl[(tc * 16 + 8 + k) * 76 + d];
        int b0 = (tc * 32) ^ ((d & 7) << 4);
        int b1 = (tc * 32 + 16) ^ ((d & 7) << 4);
        *(bf16x8*)((char*)Vtb + d * 128 + b0) = va;
        *(bf16x8*)((char*)Vtb + d * 128 + b1) = vb;
        ushort* og = VtG + (size_t)blk * 4096 + d * 64 + tc * 16;
        *(bf16x8*)og = va;
        *(bf16x8*)(og + 8) = vb;
    }
    __syncthreads();
    const int wr = wave * 16, g = lane >> 4, ccol = lane & 15;
    f32x4 acc[4] = {};
#pragma unroll
    for (int k0 = 0; k0 < 64; k0 += 32) {
        bf16x8 av = frag_ld(Vtb, wr, k0, lane);
#pragma unroll
        for (int j = 0; j < 4; ++j)
            acc[j] = __builtin_amdgcn_mfma_f32_16x16x32_bf16(av, frag_ld(Ktb, j * 16, k0, lane), acc[j], 0, 0, 0);
    }
    ushort* stg = StB + (size_t)blk * 4096;
#pragma unroll
    for (int j = 0; j < 4; ++j)
#pragma unroll
        for (int r = 0; r < 4; ++r)
            stg[(wr + g * 4 + r) * 64 + j * 16 + ccol] = f2bf(acc[j][r]);
    if (tid < 64)
        sks[(size_t)blk * 64 + tid] = skp[0][tid] + skp[1][tid] + skp[2][tid] + skp[3][tid];
}

// ---------------- parallel exclusive chunk-prefix scan (St bf16) ----------------
__global__ __launch_bounds__(256) void chunk_scan2(const ushort* __restrict__ StB,
                                                   const float* __restrict__ sks,
                                                   ushort* __restrict__ Sbf,
                                                   ushort* __restrict__ skb) {
    if (blockIdx.x < 512) {
        int id = blockIdx.x * 256 + threadIdx.x;
        int bh = id >> 12, e = id & 4095;
        const ushort* p = StB + (size_t)bh * NC_ * 4096 + e;
        ushort* q = Sbf + (size_t)bh * NC_ * 4096 + e;
        float run = 0.f;
        for (int c = 0; c < NC_; ++c) {
            q[(size_t)c * 4096] = f2bf(run);
            run += bf2f(p[(size_t)c * 4096]);
        }
    } else {
        int id2 = (blockIdx.x - 512) * 256 + threadIdx.x;
        int bh = id2 >> 6, m = id2 & 63;
        const float* p = sks + (size_t)bh * NC_ * 64 + m;
        ushort* q = skb + (size_t)bh * NC_ * 64 + m;
        float run = 0.f;
        for (int c = 0; c < NC_; ++c) {
            q[c * 64] = f2bf(run);
            run += p[c * 64];
        }
    }
}

// ---------------- chunk attention (all-MFMA) ----------------
__global__ __launch_bounds__(256) void chunk_attn_mfma(
    const ushort* __restrict__ out1, const ushort* __restrict__ VtG,
    const ushort* __restrict__ Sbf, const ushort* __restrict__ skb,
    ushort* __restrict__ attnBf)
{
    __shared__ ushort Ql[64 * 64];
    __shared__ ushort Kl[64 * 64];
    __shared__ ushort Vl[64 * 64];
    __shared__ ushort Al[64 * 64];
    __shared__ ushort Sl[80 * 64];
    const int blk = blockIdx.x, c = blk & 31, bh = blk >> 5;
    const int b = bh >> 4, h = bh & 15, t0 = c * CH_;
    const int tid = threadIdx.x, wave = tid >> 6, lane = tid & 63;
    const ushort* qg  = out1 + (size_t)(b * T_ + t0) * 3072 + h * D_;
    const ushort* kg  = qg + C_;
    const ushort* vtg = VtG + (size_t)blk * 4096;
    const ushort* sbg = Sbf + (size_t)blk * 4096;
#pragma unroll
    for (int it = 0; it < 2; ++it) {
        int i = tid + it * 256, r = i >> 3, sl = i & 7;
        int lo = (sl * 16) ^ ((r & 7) << 4);
        *(bf16x8*)((char*)Ql + r * 128 + lo) = *(const bf16x8*)(qg + (size_t)r * 3072 + sl * 8);
        *(bf16x8*)((char*)Kl + r * 128 + lo) = *(const bf16x8*)(kg + (size_t)r * 3072 + sl * 8);
        *(bf16x8*)((char*)Vl + r * 128 + lo) = *(const bf16x8*)(vtg + r * 64 + sl * 8);
        *(bf16x8*)((char*)Sl + r * 128 + lo) = *(const bf16x8*)(sbg + r * 64 + sl * 8);
    }
    if (tid < 8)
        *(bf16x8*)((char*)Sl + 64 * 128 + tid * 16) = *(const bf16x8*)(skb + (size_t)blk * 64 + tid * 8);
    __syncthreads();

    const int wr = wave * 16, g = lane >> 4, ccol = lane & 15;
    f32x4 accA[4] = {};
#pragma unroll
    for (int k0 = 0; k0 < 64; k0 += 32) {
        bf16x8 aq = frag_ld(Ql, wr, k0, lane);
#pragma unroll
        for (int j = 0; j < 4; ++j)
            accA[j] = __builtin_amdgcn_mfma_f32_16x16x32_bf16(aq, frag_ld(Kl, j * 16, k0, lane), accA[j], 0, 0, 0);
    }
    float rsum[4] = {0.f, 0.f, 0.f, 0.f};
#pragma unroll
    for (int j = 0; j < 4; ++j) {
#pragma unroll
        for (int r = 0; r < 4; ++r) {
            int tl = wr + g * 4 + r, sl2 = j * 16 + ccol;
            float v = (sl2 <= tl) ? accA[j][r] : 0.f;
            rsum[r] += v;
            *(ushort*)((char*)Al + tl * 128 + ((sl2 * 2) ^ ((tl & 7) << 4))) = f2bf(v);
        }
    }
#pragma unroll
    for (int r = 0; r < 4; ++r) {
        rsum[r] += __shfl_xor(rsum[r], 1);
        rsum[r] += __shfl_xor(rsum[r], 2);
        rsum[r] += __shfl_xor(rsum[r], 4);
        rsum[r] += __shfl_xor(rsum[r], 8);
    }
    f32x4 accC[4] = {};
    f32x4 accE = {};
#pragma unroll
    for (int k0 = 0; k0 < 64; k0 += 32) {
        bf16x8 aa = frag_ld(Al, wr, k0, lane);
#pragma unroll
        for (int j = 0; j < 4; ++j)
            accC[j] = __builtin_amdgcn_mfma_f32_16x16x32_bf16(aa, frag_ld(Vl, j * 16, k0, lane), accC[j], 0, 0, 0);
    }
#pragma unroll
    for (int k0 = 0; k0 < 64; k0 += 32) {
        bf16x8 aq = frag_ld(Ql, wr, k0, lane);
#pragma unroll
        for (int j = 0; j < 4; ++j)
            accC[j] = __builtin_amdgcn_mfma_f32_16x16x32_bf16(aq, frag_ld(Sl, j * 16, k0, lane), accC[j], 0, 0, 0);
        accE = __builtin_amdgcn_mfma_f32_16x16x32_bf16(aq, frag_ld(Sl, 64, k0, lane), accE, 0, 0, 0);
    }
    ushort* og = attnBf + (size_t)(b * T_ + t0) * C_ + h * D_;
#pragma unroll
    for (int r = 0; r < 4; ++r) {
        float nq = __shfl(accE[r], (lane & 48));
        float inv = 1.f / (nq + rsum[r] + 1e-6f);
        int tl = wr + g * 4 + r;
#pragma unroll
        for (int j = 0; j < 4; ++j)
            og[(size_t)tl * C_ + j * 16 + ccol] = f2bf(accC[j][r] * inv);
    }
}

extern "C" void kernel_launch(void* const* d_in, const int* in_sizes, int n_in,
                              void* d_out, int out_size, void* d_ws, size_t ws_size,
                              hipStream_t stream) {
    (void)in_sizes; (void)n_in; (void)out_size; (void)ws_size;
    const float* x    = (const float*)d_in[0];
    const float* Wqkv = (const float*)d_in[1];
    const float* bqkv = (const float*)d_in[2];
    const float* Wout = (const float*)d_in[3];
    const float* bout = (const float*)d_in[4];
    const float* proj = (const float*)d_in[5];
    float* out = (float*)d_out;
    char* ws = (char*)d_ws;

    ushort* Wbt    = (ushort*)(ws);                 // 6 MB
    ushort* xbf    = (ushort*)(ws + (6ull  << 20)); // 8 MB
    ushort* WoutBf = (ushort*)(ws + (14ull << 20)); // 2 MB
    ushort* attnBf = (ushort*)(ws + (16ull << 20)); // 8 MB
    float*  bbig   = (float*) (ws + (24ull << 20)); // 12 KB
    ushort* out1   = (ushort*)(ws + (25ull << 20)); // 24 MB (bf16 q'|k'|v)
    ushort* VtG    = (ushort*)(ws + (49ull << 20)); // 8 MB
    ushort* StB    = (ushort*)(ws + (57ull << 20)); // 8 MB (bf16)
    ushort* Sbf    = (ushort*)(ws + (65ull << 20)); // 8 MB
    float*  sks    = (float*) (ws + (73ull << 20)); // 256 KB
    ushort* skb    = (ushort*)(ws + (74ull << 20)); // 128 KB

    prep_all<<<NPREP_, 256, 0, stream>>>(x, Wqkv, bqkv, Wout, proj,
                                         Wbt, xbf, WoutBf, bbig);
    gemm_8phase<<<dim3(8, 32), 512, 0, stream>>>(xbf, Wbt, bbig, out1,
                                                 4096, 3072, 1024, 2048);
    chunk_kv_mfma<<<1024, 256, 0, stream>>>(out1, VtG, StB, sks);
    chunk_scan2<<<520, 256, 0, stream>>>(StB, sks, Sbf, skb);
    chunk_attn_mfma<<<1024, 256, 0, stream>>>(out1, VtG, Sbf, skb, attnBf);
    gemm2_8phase<<<dim3(8, 32), 512, 0, stream>>>(attnBf, WoutBf, bout, out,
                                                  4096, 1024, 1024);
}